// Round 1
// baseline (410.355 us; speedup 1.0000x reference)
//
#include <hip/hip_runtime.h>
#include <cstdint>
#include <cstddef>

namespace {

constexpr int kB    = 64;
constexpr int kN    = 1024;
constexpr int kE    = 655360;
constexpr int kEper = kE / kB;     // 10240
constexpr int kH    = 128;
constexpr int kK1   = 820;
constexpr int kK2   = 656;
constexpr int kM1   = kB * kN;     // 65536
constexpr int kM2   = kB * kK1;    // 52480
constexpr int kM3   = kB * kK2;    // 41984
constexpr int kRChunks = 16;       // readout row-chunks per graph

typedef __attribute__((ext_vector_type(8))) short bf16x8;
typedef __attribute__((ext_vector_type(4))) float f32x4;

__device__ inline ushort f2bf(float f) {            // fp32 -> bf16 RNE bits
  uint u = __float_as_uint(f);
  return (ushort)((u + 0x7fffu + ((u >> 16) & 1u)) >> 16);
}
__device__ inline float bf2f(ushort s) { return __uint_as_float(((uint)s) << 16); }

// inclusive block scan over 1024 threads: wave shfl-scan + 16-wavesum scan.
__device__ inline int block_scan_1024(int v, int* wsum /* LDS int[16] */) {
  const int lane = threadIdx.x & 63;
  const int w    = threadIdx.x >> 6;
#pragma unroll
  for (int off = 1; off < 64; off <<= 1) {
    const int n = __shfl_up(v, off);
    if (lane >= off) v += n;
  }
  if (lane == 63) wsum[w] = v;
  __syncthreads();
  if (w == 0) {
    int s = (lane < 16) ? wsum[lane] : 0;
#pragma unroll
    for (int off = 1; off < 16; off <<= 1) {
      const int n = __shfl_up(s, off);
      if (lane >= off) s += n;
    }
    if (lane < 16) wsum[lane] = s;
  }
  __syncthreads();
  if (w > 0) v += wsum[w - 1];
  return v;
}

// ================= prep: W^T hi/lo split + pw normalize =================
__global__ __launch_bounds__(256)
void prep_kernel(const float* __restrict__ Wl1, const float* __restrict__ Wr1,
                 const float* __restrict__ Wl2, const float* __restrict__ Wr2,
                 const float* __restrict__ pw1, const float* __restrict__ pw2,
                 ushort* __restrict__ W1h, ushort* __restrict__ W1l,
                 ushort* __restrict__ W2h, ushort* __restrict__ W2l,
                 float* __restrict__ pwn1, float* __restrict__ pwn2) {
  const int tid = threadIdx.x;
  if (blockIdx.x == 256) {
    __shared__ float sq[256];
    const float* pw = (tid < 128) ? pw1 : pw2;
    const int j = tid & 127;
    const float v = pw[j];
    sq[tid] = v * v;
    __syncthreads();
    const int base = (tid < 128) ? 0 : 128;
    float sum = 0.0f;
    for (int k = 0; k < 128; ++k) sum += sq[base + k];
    float* o = (tid < 128) ? pwn1 : pwn2;
    o[j] = v / sqrtf(sum);
    return;
  }
  const bool l2 = blockIdx.x >= 128;
  const int idx = (blockIdx.x & 127) * 256 + tid;   // 0..32767
  const int n = idx >> 8, k = idx & 255;
  const float* Wl = l2 ? Wl2 : Wl1;
  const float* Wr = l2 ? Wr2 : Wr1;
  const float w = (k < 128) ? Wl[k * kH + n] : Wr[(k - 128) * kH + n];
  const ushort h = f2bf(w);
  (l2 ? W2h : W1h)[n * 256 + k] = h;
  (l2 ? W2l : W1l)[n * 256 + k] = f2bf(w - bf2f(h));
}

// ================= layer-1 CSR build =================
__global__ void deg_kernel(const int* __restrict__ dst, int* __restrict__ deg) {
  int e = blockIdx.x * blockDim.x + threadIdx.x;
  if (e >= kE) return;
  atomicAdd(&deg[dst[e]], 1);
}

__global__ __launch_bounds__(1024)
void scan_kernel(const int* __restrict__ deg, int nloc,
                 int* __restrict__ off, int* __restrict__ cursor) {
  __shared__ int wsum[16];
  const int g = blockIdx.x, i = threadIdx.x;
  const int d = (i < nloc) ? deg[g * nloc + i] : 0;
  const int incl = block_scan_1024(d, wsum);
  if (i < nloc) {
    const int start = g * kEper + incl - d;    // exclusive scan
    off[g * nloc + i]    = start;
    cursor[g * nloc + i] = start;
  }
}

__global__ void fill1_kernel(const int* __restrict__ src, const int* __restrict__ dst,
                             int* __restrict__ cursor, int* __restrict__ ent) {
  int e = blockIdx.x * blockDim.x + threadIdx.x;
  if (e >= kE) return;
  const int pos = atomicAdd(&cursor[dst[e]], 1);
  ent[pos] = src[e];
}

// ---- ent2: layer-2 entries precomputed so gather2 has a single indirection ----
// ent2[p] = { src | keep<<30 , keep ? scoreBits : 0 }
__global__ void ent2prep_kernel(const int* __restrict__ ent,
                                const int2* __restrict__ aux,
                                int2* __restrict__ ent2) {
  int p = blockIdx.x * blockDim.x + threadIdx.x;
  if (p >= kE) return;
  const int s = ent[p];
  const int2 a = aux[s];
  ent2[p] = make_int2(s | (a.x << 30), a.x ? a.y : 0);
}

// guarded lane-parallel entry-batch loads (32 entries per half-wave in ONE instr)
__device__ inline int ldb1(const int* __restrict__ ent, int o0, int o1, int l31) {
  const int idx = o0 + l31;
  int e = 0;
  if (idx < o1) e = ent[idx];
  return e;
}
__device__ inline void ldb2(const int2* __restrict__ ent2, int o0, int o1, int l31,
                            int& ex, int& ey) {
  const int idx = o0 + l31;
  int x = 0, y = 0;
  if (idx < o1) { const int2 v = ent2[idx]; x = v.x; y = v.y; }
  ex = x; ey = y;
}

// ================= LDS-staged gather-mean (R12 redesign) =================
// Old design: per-edge 512-B row gathers from L2 (~200 cy dependent chain) ->
// 39.5 us at 25% of L2 peak, latency-bound (VALUBusy 37%, HBM 17%).
// New design: block = (graph, 16-col chunk). Stage the graph's 1024x16 f32
// slab into 64 KB LDS once (coalesced; x read exactly ONCE overall), then the
// edge loop is ds_read_b32 gathers. Half-wave owns 32 consecutive nodes;
// entries fetched 32-at-a-time lane-parallel (prefetched 1 node ahead) and
// broadcast per-edge via __shfl (ds_bpermute). 2 blocks/CU (128 KB LDS).
// Grid 64 graphs x 8 chunks = 512 blocks; blockIdx&7 keeps graph->XCD pinning.
__global__ __launch_bounds__(1024, 8)
void gather1_lds(const float* __restrict__ feat, const int* __restrict__ ent,
                 const int* __restrict__ off, const int* __restrict__ cursor,
                 float* __restrict__ aggout) {
  __shared__ float cache[1024 * 16];                 // 64 KB, stride 16 floats
  const int xcd   = blockIdx.x & 7;
  const int local = blockIdx.x >> 3;
  const int graph = xcd * 8 + (local >> 3);
  const int chunk = local & 7;
  const int tid   = threadIdx.x;
  const int gbase = graph << 10;

  // ---- stage: 1024 rows x 16 cols (64-B segments, 4 lanes/row) ----
#pragma unroll
  for (int ps = 0; ps < 4; ++ps) {
    const int row = ps * 256 + (tid >> 2);
    const int q   = (tid & 3) * 4;
    const float4 v = *(const float4*)(feat + (size_t)(gbase + row) * kH + chunk * 16 + q);
    *(float4*)&cache[row * 16 + q] = v;
  }
  // lane l31 of half-wave hw holds CSR bounds of local node tid (= hw*32+l31)
  const int ol = off[gbase + tid];
  const int cl = cursor[gbase + tid];
  __syncthreads();

  const int lane = tid & 63;
  const int hb   = lane & 32;                        // half base lane
  const int l31  = lane & 31;
  const int sg   = (lane >> 4) & 1;                  // subgroup: even/odd edges
  const int colj = lane & 15;
  const int nb   = tid & 0x3E0;                      // this half-wave's node base

  int o0c = __shfl(ol, hb);
  int o1c = __shfl(cl, hb);
  int Ec  = ldb1(ent, o0c, o1c, l31);

  for (int nn = 0; nn < 32; ++nn) {
    int o0n = 0, o1n = 0, En = 0;
    if (nn < 31) {                                   // prefetch next node's batch
      o0n = __shfl(ol, hb + nn + 1);
      o1n = __shfl(cl, hb + nn + 1);
      En  = ldb1(ent, o0n, o1n, l31);
    }
    const int deg = o1c - o0c;
    float acc = 0.0f;
    int eb = 0, E = Ec;
    while (true) {
      const int bc = min(deg - eb, 32);
      for (int i = 0; i < (bc >> 1); ++i) {
        const int er = __shfl(E, hb + 2 * i + sg) & 1023;
        acc += cache[er * 16 + colj];
      }
      if (bc & 1) {                                  // odd tail: count edge once
        const int er = __shfl(E, hb + bc - 1) & 1023;
        const float v = cache[er * 16 + colj];
        acc += sg ? 0.0f : v;
      }
      eb += 32;
      if (eb >= deg) break;                          // deg>32: essentially never
      E = ldb1(ent, o0c + eb, o1c, l31);
    }
    const float tot = acc + __shfl_xor(acc, 16);
    const float r = 1.0f / fmaxf((float)deg, 1.0f);
    if (sg == 0)
      aggout[(size_t)(gbase + nb + nn) * kH + chunk * 16 + colj] = tot * r;
    o0c = o0n; o1c = o1n; Ec = En;
  }
}

// layer-2 variant: nodes are kK1=820/graph (via perm), edges gated by keep bit
// and scaled by score (both folded into ent2 words). Same LDS staging of bufB.
__global__ __launch_bounds__(1024, 8)
void gather2_lds(const float* __restrict__ feat, const int2* __restrict__ ent2,
                 const int* __restrict__ off, const int* __restrict__ cursor,
                 const int* __restrict__ perm, float* __restrict__ aggout) {
  __shared__ float cache[1024 * 16];
  const int xcd   = blockIdx.x & 7;
  const int local = blockIdx.x >> 3;
  const int graph = xcd * 8 + (local >> 3);
  const int chunk = local & 7;
  const int tid   = threadIdx.x;
  const int gbase = graph << 10;

#pragma unroll
  for (int ps = 0; ps < 4; ++ps) {
    const int row = ps * 256 + (tid >> 2);
    const int q   = (tid & 3) * 4;
    const float4 v = *(const float4*)(feat + (size_t)(gbase + row) * kH + chunk * 16 + q);
    *(float4*)&cache[row * 16 + q] = v;
  }
  const int hw   = tid >> 5;
  const int l31w = tid & 31;
  const int myLn = hw * 26 + l31w;                   // 32 halves x 26 >= 820
  int ol = 0, cl = 0;
  if (l31w < 26 && myLn < kK1) {
    const int orig = perm[graph * kK1 + myLn];
    ol = off[orig];
    cl = cursor[orig];
  }
  __syncthreads();

  const int lane = tid & 63;
  const int hb   = lane & 32;
  const int l31  = lane & 31;
  const int sg   = (lane >> 4) & 1;
  const int colj = lane & 15;
  const int nbl  = (tid >> 5) * 26;                  // local node base of half

  int o0c = __shfl(ol, hb);
  int o1c = __shfl(cl, hb);
  int EXc, EYc;
  ldb2(ent2, o0c, o1c, l31, EXc, EYc);

  for (int nn = 0; nn < 26; ++nn) {
    int o0n = 0, o1n = 0, EXn = 0, EYn = 0;
    if (nn < 25) {
      o0n = __shfl(ol, hb + nn + 1);
      o1n = __shfl(cl, hb + nn + 1);
      ldb2(ent2, o0n, o1n, l31, EXn, EYn);
    }
    const int deg = o1c - o0c;
    float acc = 0.0f;
    int cnt = 0;
    int eb = 0, EX = EXc, EY = EYc;
    while (true) {
      const int bc = min(deg - eb, 32);
      for (int i = 0; i < (bc >> 1); ++i) {
        const int j  = hb + 2 * i + sg;
        const int ex = __shfl(EX, j);
        const int ey = __shfl(EY, j);
        acc = fmaf(cache[(ex & 1023) * 16 + colj], __int_as_float(ey), acc);
        cnt += (ex >> 30) & 1;
      }
      if (bc & 1) {
        const int j  = hb + bc - 1;
        const int ex = __shfl(EX, j);
        const int ey = __shfl(EY, j);
        const float v = cache[(ex & 1023) * 16 + colj] * __int_as_float(ey);
        acc += sg ? 0.0f : v;
        cnt += sg ? 0 : ((ex >> 30) & 1);
      }
      eb += 32;
      if (eb >= deg) break;
      ldb2(ent2, o0c + eb, o1c, l31, EX, EY);
    }
    const float tot = acc + __shfl_xor(acc, 16);
    const int   ct  = cnt + __shfl_xor(cnt, 16);
    const float r = 1.0f / fmaxf((float)ct, 1.0f);
    const int ln = nbl + nn;
    if (sg == 0 && ln < kK1)
      aggout[(size_t)(graph * kK1 + ln) * kH + chunk * 16 + colj] = tot * r;
    o0c = o0n; o1c = o1n; EXc = EXn; EYc = EYn;
  }
}

// ================= split-bf16 MFMA SAGE GEMM + fused score =================
// 64-row x 128-col block tile, 4 waves in 2x2, wave tile 32x64 (rt=2, ct=4).
__global__ __launch_bounds__(256)
void sage_gemm_mfma(const float* __restrict__ meanb, const float* __restrict__ xsrc,
                    const int* __restrict__ perm, const float* __restrict__ gsc,
                    const ushort* __restrict__ WTh, const ushort* __restrict__ WTl,
                    const float* __restrict__ bias, const float* __restrict__ pwn,
                    float* __restrict__ outp, float* __restrict__ scr) {
  __shared__ __align__(16) ushort aH[64][32];    // [row][k], 64 B row stride
  __shared__ __align__(16) ushort aL[64][32];
  __shared__ __align__(16) ushort wHs[128][32];  // [n][k] (= W^T)
  __shared__ __align__(16) ushort wLs[128][32];
  __shared__ float sdot[64][2];                  // [row][col-half] score partials
  const int tid  = threadIdx.x;
  const int wid  = tid >> 6;
  const int lane = tid & 63;
  const int quad = lane >> 4;
  const int l16  = lane & 15;
  const int rowbase = blockIdx.x * 64;
  const int wr = (wid >> 1) * 32;                // wave row offset (0/32)
  const int wc = (wid & 1) * 64;                 // wave col offset (0/64)

  f32x4 acc[2][4];
#pragma unroll
  for (int a = 0; a < 2; ++a)
#pragma unroll
    for (int b = 0; b < 4; ++b) acc[a][b] = (f32x4){0.f, 0.f, 0.f, 0.f};

  for (int s = 0; s < 8; ++s) {                  // 8 k-steps of 32 over K=256
    const bool ismean = s < 4;
    const float* sp = ismean ? meanb : xsrc;
    const int kbase = s * 32;
    const int kloc  = ismean ? kbase : kbase - 128;
    // ---- stage A (fp32 -> bf16 hi/lo): 64 rows x 32 k ----
#pragma unroll
    for (int i = 0; i < 2; ++i) {
      const int p   = tid + i * 256;
      const int row = p >> 3;
      const int k4  = (p & 7) * 4;
      const int grow = rowbase + row;
      int srow = grow; float scale = 1.0f;
      if (perm) { if (!ismean) { srow = perm[grow]; scale = gsc[grow]; } }
      const float4 v = *(const float4*)(sp + (size_t)srow * kH + kloc + k4);
      float f[4] = {v.x * scale, v.y * scale, v.z * scale, v.w * scale};
      ushort4 hv, lv;
      hv.x = f2bf(f[0]); lv.x = f2bf(f[0] - bf2f(hv.x));
      hv.y = f2bf(f[1]); lv.y = f2bf(f[1] - bf2f(hv.y));
      hv.z = f2bf(f[2]); lv.z = f2bf(f[2] - bf2f(hv.z));
      hv.w = f2bf(f[3]); lv.w = f2bf(f[3] - bf2f(hv.w));
      *(ushort4*)&aH[row][k4] = hv;
      *(ushort4*)&aL[row][k4] = lv;
    }
    // ---- stage W^T hi/lo: 128 n x 32 k ----
#pragma unroll
    for (int i = 0; i < 4; ++i) {
      const int p  = tid + i * 256;
      const int n  = p >> 3;
      const int k4 = (p & 7) * 4;
      *(ushort4*)&wHs[n][k4] = *(const ushort4*)(WTh + n * 256 + kbase + k4);
      *(ushort4*)&wLs[n][k4] = *(const ushort4*)(WTl + n * 256 + kbase + k4);
    }
    __syncthreads();
    bf16x8 afh[2], afl[2];
#pragma unroll
    for (int rt = 0; rt < 2; ++rt) {
      afh[rt] = *(const bf16x8*)&aH[wr + rt * 16 + l16][quad * 8];
      afl[rt] = *(const bf16x8*)&aL[wr + rt * 16 + l16][quad * 8];
    }
#pragma unroll
    for (int ct = 0; ct < 4; ++ct) {
      const bf16x8 bh = *(const bf16x8*)&wHs[wc + ct * 16 + l16][quad * 8];
      const bf16x8 bl = *(const bf16x8*)&wLs[wc + ct * 16 + l16][quad * 8];
#pragma unroll
      for (int rt = 0; rt < 2; ++rt) {
        acc[rt][ct] = __builtin_amdgcn_mfma_f32_16x16x32_bf16(afh[rt], bh, acc[rt][ct], 0, 0, 0);
        acc[rt][ct] = __builtin_amdgcn_mfma_f32_16x16x32_bf16(afh[rt], bl, acc[rt][ct], 0, 0, 0);
        acc[rt][ct] = __builtin_amdgcn_mfma_f32_16x16x32_bf16(afl[rt], bh, acc[rt][ct], 0, 0, 0);
      }
    }
    __syncthreads();
  }
  // ---- epilogue: bias + relu + store + fused score (64-col partial/wave) ----
  float bv[4], pwv[4];
#pragma unroll
  for (int ct = 0; ct < 4; ++ct) {
    const int col = wc + ct * 16 + l16;
    bv[ct]  = bias[col];
    pwv[ct] = pwn[col];
  }
  float dot[2][4];
#pragma unroll
  for (int rt = 0; rt < 2; ++rt)
#pragma unroll
    for (int reg = 0; reg < 4; ++reg) dot[rt][reg] = 0.0f;
#pragma unroll
  for (int ct = 0; ct < 4; ++ct) {
    const int col = wc + ct * 16 + l16;
#pragma unroll
    for (int rt = 0; rt < 2; ++rt) {
#pragma unroll
      for (int reg = 0; reg < 4; ++reg) {
        const int row = rowbase + wr + rt * 16 + quad * 4 + reg;
        const float o = fmaxf(acc[rt][ct][reg] + bv[ct], 0.0f);
        outp[(size_t)row * kH + col] = o;
        dot[rt][reg] += o * pwv[ct];
      }
    }
  }
#pragma unroll
  for (int rt = 0; rt < 2; ++rt) {
#pragma unroll
    for (int reg = 0; reg < 4; ++reg) {
      float d = dot[rt][reg];
      d += __shfl_xor(d, 1);
      d += __shfl_xor(d, 2);
      d += __shfl_xor(d, 4);
      d += __shfl_xor(d, 8);
      if (l16 == 0) sdot[wr + rt * 16 + quad * 4 + reg][wc >> 6] = d;
    }
  }
  __syncthreads();
  if (tid < 64) scr[rowbase + tid] = tanhf(sdot[tid][0] + sdot[tid][1]);
}

// ---- top-K rank phase: 4 chunk-blocks per graph, one thread per node ----
__global__ __launch_bounds__(256)
void rank_kernel(const float* __restrict__ scr, int n_per, int K,
                 int* __restrict__ kflag) {
  __shared__ __align__(16) float s[1024];
  const int g     = blockIdx.x >> 2;
  const int chunk = blockIdx.x & 3;
  const int tid   = threadIdx.x;
  for (int i = tid; i < 1024; i += 256)
    s[i] = (i < n_per) ? scr[g * n_per + i] : -3e30f;   // pad never outranks
  __syncthreads();
  const int i0 = chunk * 256 + tid;
  if (i0 >= n_per) return;
  const float mys = s[i0];
  int rank = 0;
  for (int j = 0; j < 1024; j += 4) {
    const float4 sj = *(const float4*)&s[j];
    rank += (sj.x > mys) || (sj.x == mys && (j + 0) < i0);
    rank += (sj.y > mys) || (sj.y == mys && (j + 1) < i0);
    rank += (sj.z > mys) || (sj.z == mys && (j + 2) < i0);
    rank += (sj.w > mys) || (sj.w == mys && (j + 3) < i0);
  }
  kflag[g * n_per + i0] = (rank < K) ? 1 : 0;
}

// ---- compaction: per-graph scan of keep flags; aux={keep,score} for layer1 ----
__global__ __launch_bounds__(1024)
void compact_kernel(const float* __restrict__ scr, const int* __restrict__ kflag,
                    int n_per, int K, int* __restrict__ perm,
                    float* __restrict__ gsc, int2* __restrict__ aux) {
  __shared__ int wsum[16];
  const int g = blockIdx.x, i = threadIdx.x;
  const int keep = (i < n_per) ? kflag[g * n_per + i] : 0;
  const int incl = block_scan_1024(keep, wsum);
  if (i < n_per) {
    const float sc = scr[g * n_per + i];
    if (keep) {
      const int pos = incl - 1;
      perm[g * K + pos] = g * n_per + i;
      gsc[g * K + pos]  = sc;
    }
    if (aux) aux[g * n_per + i] = make_int2(keep, __float_as_int(sc));
  }
}

// ---- readout stage 1: per-(graph, row-chunk) partial mean/max over gated rows ----
__global__ __launch_bounds__(256)
void readout_part(const float* __restrict__ h, const int* __restrict__ perm,
                  const float* __restrict__ gsc, int K,
                  float* __restrict__ psum, float* __restrict__ pmax) {
  const int g     = blockIdx.x >> 4;
  const int chunk = blockIdx.x & (kRChunks - 1);
  const int j     = threadIdx.x & 127;
  const int part  = threadIdx.x >> 7;            // 2 parts
  const int rows  = (K + kRChunks - 1) / kRChunks;
  const int r0 = chunk * rows;
  const int r1 = min(r0 + rows, K);
  float sum = 0.0f, mx = -1e30f;
  for (int r = r0 + part; r < r1; r += 2) {
    const int   row = perm[g * K + r];
    const float sc  = gsc[g * K + r];
    const float v   = h[(size_t)row * kH + j] * sc;
    sum += v;
    mx = fmaxf(mx, v);
  }
  __shared__ float ss[2][128], sm[2][128];
  ss[part][j] = sum;
  sm[part][j] = mx;
  __syncthreads();
  if (part == 0) {
    sum += ss[1][j];
    mx = fmaxf(mx, sm[1][j]);
    psum[(size_t)blockIdx.x * 128 + j] = sum;
    pmax[(size_t)blockIdx.x * 128 + j] = mx;
  }
}

// ---- fused: combine readout chunks (both layers) + 2-layer MLP head ----
__global__ __launch_bounds__(128)
void final_mlp(const float* __restrict__ ps1, const float* __restrict__ pm1,
               const float* __restrict__ ps2, const float* __restrict__ pm2,
               const float* __restrict__ fW1, const float* __restrict__ fb1,
               const float* __restrict__ fW2, const float* __restrict__ fb2,
               float* __restrict__ out) {
  __shared__ float xx[256];
  __shared__ float z[128];
  const int g = blockIdx.x, tid = threadIdx.x;
  float s1 = 0.f, m1 = -1e30f, s2 = 0.f, m2 = -1e30f;
#pragma unroll
  for (int c = 0; c < kRChunks; ++c) {
    s1 += ps1[(size_t)(g * kRChunks + c) * 128 + tid];
    m1 = fmaxf(m1, pm1[(size_t)(g * kRChunks + c) * 128 + tid]);
    s2 += ps2[(size_t)(g * kRChunks + c) * 128 + tid];
    m2 = fmaxf(m2, pm2[(size_t)(g * kRChunks + c) * 128 + tid]);
  }
  xx[tid]       = s1 / (float)kK1 + s2 / (float)kK2;
  xx[tid + 128] = m1 + m2;
  __syncthreads();
  float a = fb1[tid];
  for (int k = 0; k < 256; ++k) a += xx[k] * fW1[k * 128 + tid];
  z[tid] = fmaxf(a, 0.0f);
  __syncthreads();
  if (tid < 10) {
    float o = fb2[tid];
    for (int k = 0; k < 128; ++k) o += z[k] * fW2[k * 10 + tid];
    out[g * 10 + tid] = o;
  }
}

}  // namespace

extern "C" void kernel_launch(void* const* d_in, const int* in_sizes, int n_in,
                              void* d_out, int out_size, void* d_ws, size_t ws_size,
                              hipStream_t stream) {
  const float* x   = (const float*)d_in[0];
  const int*   ei  = (const int*)d_in[1];
  const float* Wl1 = (const float*)d_in[3];
  const float* bl1 = (const float*)d_in[4];
  const float* Wr1 = (const float*)d_in[5];
  const float* Wl2 = (const float*)d_in[6];
  const float* bl2 = (const float*)d_in[7];
  const float* Wr2 = (const float*)d_in[8];
  const float* pw1 = (const float*)d_in[9];
  const float* pw2 = (const float*)d_in[10];
  const float* fW1 = (const float*)d_in[11];
  const float* fb1 = (const float*)d_in[12];
  const float* fW2 = (const float*)d_in[13];
  const float* fb2 = (const float*)d_in[14];
  const int* src = ei;
  const int* dst = ei + kE;
  (void)in_sizes; (void)n_in; (void)out_size; (void)ws_size;

  char* wsb = (char*)d_ws;
  size_t off_b = 0;
  auto alloc = [&](size_t bytes) {
    void* p = wsb + off_b;
    off_b += (bytes + 255) & ~(size_t)255;
    return p;
  };
  float* bufA = (float*)alloc((size_t)kM1 * kH * 4);  // mean1 -> mean2
  float* bufB = (float*)alloc((size_t)kM1 * kH * 4);  // h1
  float* bufC = (float*)alloc((size_t)kM2 * kH * 4);  // h2
  int*   deg  = (int*)alloc((size_t)kM1 * 4);
  int*   coff = (int*)alloc((size_t)kM1 * 4);
  int*   ccur = (int*)alloc((size_t)kM1 * 4);
  int*   ent  = (int*)alloc((size_t)kE * 4);
  int2*  ent2 = (int2*)alloc((size_t)kE * 8);
  float* scr  = (float*)alloc((size_t)kM1 * 4);
  int*   kflag= (int*)alloc((size_t)kM1 * 4);
  int2*  aux  = (int2*)alloc((size_t)kM1 * 8);
  int*   perm1= (int*)alloc((size_t)kM2 * 4);
  float* gsc1 = (float*)alloc((size_t)kM2 * 4);
  int*   perm2= (int*)alloc((size_t)kM3 * 4);
  float* gsc2 = (float*)alloc((size_t)kM3 * 4);
  float* psum1= (float*)alloc((size_t)kB * kRChunks * 128 * 4);
  float* pmax1= (float*)alloc((size_t)kB * kRChunks * 128 * 4);
  float* psum2= (float*)alloc((size_t)kB * kRChunks * 128 * 4);
  float* pmax2= (float*)alloc((size_t)kB * kRChunks * 128 * 4);
  ushort* wt1h = (ushort*)alloc((size_t)128 * 256 * 2);
  ushort* wt1l = (ushort*)alloc((size_t)128 * 256 * 2);
  ushort* wt2h = (ushort*)alloc((size_t)128 * 256 * 2);
  ushort* wt2l = (ushort*)alloc((size_t)128 * 256 * 2);
  float* pwn1 = (float*)alloc(128 * 4);
  float* pwn2 = (float*)alloc(128 * 4);

  prep_kernel<<<257, 256, 0, stream>>>(Wl1, Wr1, Wl2, Wr2, pw1, pw2,
                                       wt1h, wt1l, wt2h, wt2l, pwn1, pwn2);

  // ---------------- layer 1 ----------------
  hipMemsetAsync(deg, 0, (size_t)kM1 * 4, stream);
  deg_kernel<<<kE / 256, 256, 0, stream>>>(dst, deg);
  scan_kernel<<<kB, 1024, 0, stream>>>(deg, kN, coff, ccur);
  fill1_kernel<<<kE / 256, 256, 0, stream>>>(src, dst, ccur, ent);
  gather1_lds<<<kB * 8, 1024, 0, stream>>>(x, ent, coff, ccur, bufA);
  sage_gemm_mfma<<<kM1 / 64, 256, 0, stream>>>(bufA, x, nullptr, nullptr,
                                               wt1h, wt1l, bl1, pwn1, bufB, scr);
  rank_kernel<<<kB * 4, 256, 0, stream>>>(scr, kN, kK1, kflag);
  compact_kernel<<<kB, 1024, 0, stream>>>(scr, kflag, kN, kK1, perm1, gsc1, aux);
  readout_part<<<kB * kRChunks, 256, 0, stream>>>(bufB, perm1, gsc1, kK1, psum1, pmax1);

  // ---------------- layer 2 (reuses layer-1 CSR; ent2 folds aux in) ----------------
  ent2prep_kernel<<<kE / 256, 256, 0, stream>>>(ent, aux, ent2);
  gather2_lds<<<kB * 8, 1024, 0, stream>>>(bufB, ent2, coff, ccur, perm1, bufA);
  sage_gemm_mfma<<<kM2 / 64, 256, 0, stream>>>(bufA, bufB, perm1, gsc1,
                                               wt2h, wt2l, bl2, pwn2, bufC, scr);
  rank_kernel<<<kB * 4, 256, 0, stream>>>(scr, kK1, kK2, kflag);
  compact_kernel<<<kB, 1024, 0, stream>>>(scr, kflag, kK1, kK2, perm2, gsc2, nullptr);
  readout_part<<<kB * kRChunks, 256, 0, stream>>>(bufC, perm2, gsc2, kK2, psum2, pmax2);

  // ---------------- head ----------------
  final_mlp<<<kB, 128, 0, stream>>>(psum1, pmax1, psum2, pmax2,
                                    fW1, fb1, fW2, fb2, (float*)d_out);
}

// Round 2
// 363.372 us; speedup vs baseline: 1.1293x; 1.1293x over previous
//
#include <hip/hip_runtime.h>
#include <cstdint>
#include <cstddef>

namespace {

constexpr int kB    = 64;
constexpr int kN    = 1024;
constexpr int kE    = 655360;
constexpr int kEper = kE / kB;     // 10240
constexpr int kH    = 128;
constexpr int kK1   = 820;
constexpr int kK2   = 656;
constexpr int kM1   = kB * kN;     // 65536
constexpr int kM2   = kB * kK1;    // 52480
constexpr int kM3   = kB * kK2;    // 41984
constexpr int kRChunks = 16;       // readout row-chunks per graph

typedef __attribute__((ext_vector_type(8))) short bf16x8;
typedef __attribute__((ext_vector_type(4))) float f32x4;

__device__ inline ushort f2bf(float f) {            // fp32 -> bf16 RNE bits
  uint u = __float_as_uint(f);
  return (ushort)((u + 0x7fffu + ((u >> 16) & 1u)) >> 16);
}
__device__ inline float bf2f(ushort s) { return __uint_as_float(((uint)s) << 16); }

// inclusive block scan over 1024 threads: wave shfl-scan + 16-wavesum scan.
__device__ inline int block_scan_1024(int v, int* wsum /* LDS int[16] */) {
  const int lane = threadIdx.x & 63;
  const int w    = threadIdx.x >> 6;
#pragma unroll
  for (int off = 1; off < 64; off <<= 1) {
    const int n = __shfl_up(v, off);
    if (lane >= off) v += n;
  }
  if (lane == 63) wsum[w] = v;
  __syncthreads();
  if (w == 0) {
    int s = (lane < 16) ? wsum[lane] : 0;
#pragma unroll
    for (int off = 1; off < 16; off <<= 1) {
      const int n = __shfl_up(s, off);
      if (lane >= off) s += n;
    }
    if (lane < 16) wsum[lane] = s;
  }
  __syncthreads();
  if (w > 0) v += wsum[w - 1];
  return v;
}

// ================= prep: W^T hi/lo split + pw normalize =================
__global__ __launch_bounds__(256)
void prep_kernel(const float* __restrict__ Wl1, const float* __restrict__ Wr1,
                 const float* __restrict__ Wl2, const float* __restrict__ Wr2,
                 const float* __restrict__ pw1, const float* __restrict__ pw2,
                 ushort* __restrict__ W1h, ushort* __restrict__ W1l,
                 ushort* __restrict__ W2h, ushort* __restrict__ W2l,
                 float* __restrict__ pwn1, float* __restrict__ pwn2) {
  const int tid = threadIdx.x;
  if (blockIdx.x == 256) {
    __shared__ float sq[256];
    const float* pw = (tid < 128) ? pw1 : pw2;
    const int j = tid & 127;
    const float v = pw[j];
    sq[tid] = v * v;
    __syncthreads();
    const int base = (tid < 128) ? 0 : 128;
    float sum = 0.0f;
    for (int k = 0; k < 128; ++k) sum += sq[base + k];
    float* o = (tid < 128) ? pwn1 : pwn2;
    o[j] = v / sqrtf(sum);
    return;
  }
  const bool l2 = blockIdx.x >= 128;
  const int idx = (blockIdx.x & 127) * 256 + tid;   // 0..32767
  const int n = idx >> 8, k = idx & 255;
  const float* Wl = l2 ? Wl2 : Wl1;
  const float* Wr = l2 ? Wr2 : Wr1;
  const float w = (k < 128) ? Wl[k * kH + n] : Wr[(k - 128) * kH + n];
  const ushort h = f2bf(w);
  (l2 ? W2h : W1h)[n * 256 + k] = h;
  (l2 ? W2l : W1l)[n * 256 + k] = f2bf(w - bf2f(h));
}

// ================= layer-1 CSR build =================
__global__ void deg_kernel(const int* __restrict__ dst, int* __restrict__ deg) {
  int e = blockIdx.x * blockDim.x + threadIdx.x;
  if (e >= kE) return;
  atomicAdd(&deg[dst[e]], 1);
}

__global__ __launch_bounds__(1024)
void scan_kernel(const int* __restrict__ deg, int nloc,
                 int* __restrict__ off, int* __restrict__ cursor) {
  __shared__ int wsum[16];
  const int g = blockIdx.x, i = threadIdx.x;
  const int d = (i < nloc) ? deg[g * nloc + i] : 0;
  const int incl = block_scan_1024(d, wsum);
  if (i < nloc) {
    const int start = g * kEper + incl - d;    // exclusive scan
    off[g * nloc + i]    = start;
    cursor[g * nloc + i] = start;
  }
}

// stores GRAPH-LOCAL src ids (src and dst are always in the same graph;
// N=1024 pow2) so the gather kernels index their LDS cache directly.
__global__ void fill1_kernel(const int* __restrict__ src, const int* __restrict__ dst,
                             int* __restrict__ cursor, int* __restrict__ ent) {
  int e = blockIdx.x * blockDim.x + threadIdx.x;
  if (e >= kE) return;
  const int pos = atomicAdd(&cursor[dst[e]], 1);
  ent[pos] = src[e] & (kN - 1);
}

// ---- ent2: layer-2 entries precomputed so gather2 has a single indirection ----
// ent2[p] = { src_local | keep<<30 , keep ? scoreBits : 0 }
__global__ void ent2prep_kernel(const int* __restrict__ ent,
                                const int2* __restrict__ aux,
                                int2* __restrict__ ent2) {
  int p = blockIdx.x * blockDim.x + threadIdx.x;
  if (p >= kE) return;
  const int sloc = ent[p];
  const int g    = p / kEper;                 // CSR positions are graph-contiguous
  const int2 a = aux[g * kN + sloc];
  ent2[p] = make_int2(sloc | (a.x << 30), a.x ? a.y : 0);
}

// ================= LDS-staged gather-mean, v2 (R13) =================
// R12 post-mortem: __shfl broadcast = ds_bpermute = LDS-pipe op; with per-edge
// b32 reads the edge loop paid 2 LDS instrs / 4 edges (+1M bank-conflict cy)
// -> 63 us. v2 removes ALL cross-lane ops: a 4-lane group owns one node, each
// lane holds 4 cols (float4 acc). Per edge one ds_read_b128 slot: a wave
// instruction covers 16 edges x 64 B = 1024 B payload (4x R12). Edge ids are
// loaded by all 4 lanes at the SAME address (hw-broadcast global load, ids are
// graph-local), prefetched 4-deep so L2 latency hides under ~600 cy of
// overlapped work across 8 waves/SIMD. Degree divergence across the 16 groups
// costs only exec-masked (bank-free) slots. No epilogue reduction at all.
__global__ __launch_bounds__(1024, 8)
void gather1_lds(const float* __restrict__ feat, const int* __restrict__ ent,
                 const int* __restrict__ off, const int* __restrict__ cursor,
                 float* __restrict__ aggout) {
  __shared__ float cache[1024 * 16];                 // 64 KB, stride 16 floats
  const int xcd   = blockIdx.x & 7;
  const int local = blockIdx.x >> 3;
  const int graph = xcd * 8 + (local >> 3);
  const int chunk = local & 7;
  const int tid   = threadIdx.x;
  const int gbase = graph << 10;

  // ---- stage: 1024 rows x 16 cols (64-B segments, 4 lanes/row) ----
#pragma unroll
  for (int ps = 0; ps < 4; ++ps) {
    const int row = ps * 256 + (tid >> 2);
    const int q   = (tid & 3) * 4;
    const float4 v = *(const float4*)(feat + (size_t)(gbase + row) * kH + chunk * 16 + q);
    *(float4*)&cache[row * 16 + q] = v;
  }
  __syncthreads();

  const int grp = tid >> 2;            // group id 0..255 = node within iter
  const int q4  = (tid & 3) * 4;       // this lane's 4 cols inside the chunk

  for (int it = 0; it < 4; ++it) {
    const int lnode = it * 256 + grp;
    const int node  = gbase + lnode;
    const int o0 = off[node];
    const int o1 = cursor[node];
    const int deg = o1 - o0;
    float4 acc = make_float4(0.f, 0.f, 0.f, 0.f);
    int pf[4];
#pragma unroll
    for (int i = 0; i < 4; ++i) pf[i] = (o0 + i < o1) ? ent[o0 + i] : 0;
    for (int eb = 0; eb < deg; eb += 4) {
      int nx[4];
#pragma unroll
      for (int i = 0; i < 4; ++i) {
        const int idx = o0 + eb + 4 + i;
        nx[i] = (idx < o1) ? ent[idx] : 0;
      }
#pragma unroll
      for (int i = 0; i < 4; ++i) {
        const float m = (eb + i < deg) ? 1.0f : 0.0f;   // mask tail (row 0 reads broadcast, free)
        const float4 v = *(const float4*)&cache[pf[i] * 16 + q4];
        acc.x = fmaf(v.x, m, acc.x);
        acc.y = fmaf(v.y, m, acc.y);
        acc.z = fmaf(v.z, m, acc.z);
        acc.w = fmaf(v.w, m, acc.w);
      }
#pragma unroll
      for (int i = 0; i < 4; ++i) pf[i] = nx[i];
    }
    const float r = 1.0f / fmaxf((float)deg, 1.0f);
    const f32x4 res = {acc.x * r, acc.y * r, acc.z * r, acc.w * r};
    __builtin_nontemporal_store(res, (f32x4*)(aggout + (size_t)node * kH + chunk * 16 + q4));
  }
}

// layer-2 variant: 820 kept nodes/graph via perm; keep bit + score folded into
// ent2 words, so guarded-out / dropped edges contribute exactly 0 with NO
// in-body mask (score word is 0). cnt counts kept edges only.
__global__ __launch_bounds__(1024, 8)
void gather2_lds(const float* __restrict__ feat, const int2* __restrict__ ent2,
                 const int* __restrict__ off, const int* __restrict__ cursor,
                 const int* __restrict__ perm, float* __restrict__ aggout) {
  __shared__ float cache[1024 * 16];
  const int xcd   = blockIdx.x & 7;
  const int local = blockIdx.x >> 3;
  const int graph = xcd * 8 + (local >> 3);
  const int chunk = local & 7;
  const int tid   = threadIdx.x;
  const int gbase = graph << 10;

#pragma unroll
  for (int ps = 0; ps < 4; ++ps) {
    const int row = ps * 256 + (tid >> 2);
    const int q   = (tid & 3) * 4;
    const float4 v = *(const float4*)(feat + (size_t)(gbase + row) * kH + chunk * 16 + q);
    *(float4*)&cache[row * 16 + q] = v;
  }
  __syncthreads();

  const int grp = tid >> 2;
  const int q4  = (tid & 3) * 4;

  for (int it = 0; it < 4; ++it) {
    const int lnode = it * 256 + grp;                // valid < kK1 (820)
    int o0 = 0, o1 = 0;
    if (lnode < kK1) {
      const int orig = perm[graph * kK1 + lnode];
      o0 = off[orig];
      o1 = cursor[orig];
    }
    const int deg = o1 - o0;
    float4 acc = make_float4(0.f, 0.f, 0.f, 0.f);
    int cnt = 0;
    long long pf[4];
#pragma unroll
    for (int i = 0; i < 4; ++i)
      pf[i] = (o0 + i < o1) ? *((const long long*)ent2 + o0 + i) : 0ll;
    for (int eb = 0; eb < deg; eb += 4) {
      long long nx[4];
#pragma unroll
      for (int i = 0; i < 4; ++i) {
        const int idx = o0 + eb + 4 + i;
        nx[i] = (idx < o1) ? *((const long long*)ent2 + idx) : 0ll;
      }
#pragma unroll
      for (int i = 0; i < 4; ++i) {
        const int   ex = (int)(pf[i] & 0xFFFFFFFFll);
        const float s  = __int_as_float((int)(pf[i] >> 32));  // 0 if dropped/tail
        const int   er = ex & 1023;
        cnt += (ex >> 30) & 1;
        const float4 v = *(const float4*)&cache[er * 16 + q4];
        acc.x = fmaf(v.x, s, acc.x);
        acc.y = fmaf(v.y, s, acc.y);
        acc.z = fmaf(v.z, s, acc.z);
        acc.w = fmaf(v.w, s, acc.w);
      }
#pragma unroll
      for (int i = 0; i < 4; ++i) pf[i] = nx[i];
    }
    const float r = 1.0f / fmaxf((float)cnt, 1.0f);
    const f32x4 res = {acc.x * r, acc.y * r, acc.z * r, acc.w * r};
    if (lnode < kK1)
      __builtin_nontemporal_store(res,
          (f32x4*)(aggout + (size_t)(graph * kK1 + lnode) * kH + chunk * 16 + q4));
  }
}

// ================= split-bf16 MFMA SAGE GEMM + fused score =================
// 64-row x 128-col block tile, 4 waves in 2x2, wave tile 32x64 (rt=2, ct=4).
__global__ __launch_bounds__(256)
void sage_gemm_mfma(const float* __restrict__ meanb, const float* __restrict__ xsrc,
                    const int* __restrict__ perm, const float* __restrict__ gsc,
                    const ushort* __restrict__ WTh, const ushort* __restrict__ WTl,
                    const float* __restrict__ bias, const float* __restrict__ pwn,
                    float* __restrict__ outp, float* __restrict__ scr) {
  __shared__ __align__(16) ushort aH[64][32];    // [row][k], 64 B row stride
  __shared__ __align__(16) ushort aL[64][32];
  __shared__ __align__(16) ushort wHs[128][32];  // [n][k] (= W^T)
  __shared__ __align__(16) ushort wLs[128][32];
  __shared__ float sdot[64][2];                  // [row][col-half] score partials
  const int tid  = threadIdx.x;
  const int wid  = tid >> 6;
  const int lane = tid & 63;
  const int quad = lane >> 4;
  const int l16  = lane & 15;
  const int rowbase = blockIdx.x * 64;
  const int wr = (wid >> 1) * 32;                // wave row offset (0/32)
  const int wc = (wid & 1) * 64;                 // wave col offset (0/64)

  f32x4 acc[2][4];
#pragma unroll
  for (int a = 0; a < 2; ++a)
#pragma unroll
    for (int b = 0; b < 4; ++b) acc[a][b] = (f32x4){0.f, 0.f, 0.f, 0.f};

  for (int s = 0; s < 8; ++s) {                  // 8 k-steps of 32 over K=256
    const bool ismean = s < 4;
    const float* sp = ismean ? meanb : xsrc;
    const int kbase = s * 32;
    const int kloc  = ismean ? kbase : kbase - 128;
    // ---- stage A (fp32 -> bf16 hi/lo): 64 rows x 32 k ----
#pragma unroll
    for (int i = 0; i < 2; ++i) {
      const int p   = tid + i * 256;
      const int row = p >> 3;
      const int k4  = (p & 7) * 4;
      const int grow = rowbase + row;
      int srow = grow; float scale = 1.0f;
      if (perm) { if (!ismean) { srow = perm[grow]; scale = gsc[grow]; } }
      const float4 v = *(const float4*)(sp + (size_t)srow * kH + kloc + k4);
      float f[4] = {v.x * scale, v.y * scale, v.z * scale, v.w * scale};
      ushort4 hv, lv;
      hv.x = f2bf(f[0]); lv.x = f2bf(f[0] - bf2f(hv.x));
      hv.y = f2bf(f[1]); lv.y = f2bf(f[1] - bf2f(hv.y));
      hv.z = f2bf(f[2]); lv.z = f2bf(f[2] - bf2f(hv.z));
      hv.w = f2bf(f[3]); lv.w = f2bf(f[3] - bf2f(hv.w));
      *(ushort4*)&aH[row][k4] = hv;
      *(ushort4*)&aL[row][k4] = lv;
    }
    // ---- stage W^T hi/lo: 128 n x 32 k ----
#pragma unroll
    for (int i = 0; i < 4; ++i) {
      const int p  = tid + i * 256;
      const int n  = p >> 3;
      const int k4 = (p & 7) * 4;
      *(ushort4*)&wHs[n][k4] = *(const ushort4*)(WTh + n * 256 + kbase + k4);
      *(ushort4*)&wLs[n][k4] = *(const ushort4*)(WTl + n * 256 + kbase + k4);
    }
    __syncthreads();
    bf16x8 afh[2], afl[2];
#pragma unroll
    for (int rt = 0; rt < 2; ++rt) {
      afh[rt] = *(const bf16x8*)&aH[wr + rt * 16 + l16][quad * 8];
      afl[rt] = *(const bf16x8*)&aL[wr + rt * 16 + l16][quad * 8];
    }
#pragma unroll
    for (int ct = 0; ct < 4; ++ct) {
      const bf16x8 bh = *(const bf16x8*)&wHs[wc + ct * 16 + l16][quad * 8];
      const bf16x8 bl = *(const bf16x8*)&wLs[wc + ct * 16 + l16][quad * 8];
#pragma unroll
      for (int rt = 0; rt < 2; ++rt) {
        acc[rt][ct] = __builtin_amdgcn_mfma_f32_16x16x32_bf16(afh[rt], bh, acc[rt][ct], 0, 0, 0);
        acc[rt][ct] = __builtin_amdgcn_mfma_f32_16x16x32_bf16(afh[rt], bl, acc[rt][ct], 0, 0, 0);
        acc[rt][ct] = __builtin_amdgcn_mfma_f32_16x16x32_bf16(afl[rt], bh, acc[rt][ct], 0, 0, 0);
      }
    }
    __syncthreads();
  }
  // ---- epilogue: bias + relu + store + fused score (64-col partial/wave) ----
  float bv[4], pwv[4];
#pragma unroll
  for (int ct = 0; ct < 4; ++ct) {
    const int col = wc + ct * 16 + l16;
    bv[ct]  = bias[col];
    pwv[ct] = pwn[col];
  }
  float dot[2][4];
#pragma unroll
  for (int rt = 0; rt < 2; ++rt)
#pragma unroll
    for (int reg = 0; reg < 4; ++reg) dot[rt][reg] = 0.0f;
#pragma unroll
  for (int ct = 0; ct < 4; ++ct) {
    const int col = wc + ct * 16 + l16;
#pragma unroll
    for (int rt = 0; rt < 2; ++rt) {
#pragma unroll
      for (int reg = 0; reg < 4; ++reg) {
        const int row = rowbase + wr + rt * 16 + quad * 4 + reg;
        const float o = fmaxf(acc[rt][ct][reg] + bv[ct], 0.0f);
        outp[(size_t)row * kH + col] = o;
        dot[rt][reg] += o * pwv[ct];
      }
    }
  }
#pragma unroll
  for (int rt = 0; rt < 2; ++rt) {
#pragma unroll
    for (int reg = 0; reg < 4; ++reg) {
      float d = dot[rt][reg];
      d += __shfl_xor(d, 1);
      d += __shfl_xor(d, 2);
      d += __shfl_xor(d, 4);
      d += __shfl_xor(d, 8);
      if (l16 == 0) sdot[wr + rt * 16 + quad * 4 + reg][wc >> 6] = d;
    }
  }
  __syncthreads();
  if (tid < 64) scr[rowbase + tid] = tanhf(sdot[tid][0] + sdot[tid][1]);
}

// ---- top-K rank phase: 4 chunk-blocks per graph, one thread per node ----
__global__ __launch_bounds__(256)
void rank_kernel(const float* __restrict__ scr, int n_per, int K,
                 int* __restrict__ kflag) {
  __shared__ __align__(16) float s[1024];
  const int g     = blockIdx.x >> 2;
  const int chunk = blockIdx.x & 3;
  const int tid   = threadIdx.x;
  for (int i = tid; i < 1024; i += 256)
    s[i] = (i < n_per) ? scr[g * n_per + i] : -3e30f;   // pad never outranks
  __syncthreads();
  const int i0 = chunk * 256 + tid;
  if (i0 >= n_per) return;
  const float mys = s[i0];
  int rank = 0;
  for (int j = 0; j < 1024; j += 4) {
    const float4 sj = *(const float4*)&s[j];
    rank += (sj.x > mys) || (sj.x == mys && (j + 0) < i0);
    rank += (sj.y > mys) || (sj.y == mys && (j + 1) < i0);
    rank += (sj.z > mys) || (sj.z == mys && (j + 2) < i0);
    rank += (sj.w > mys) || (sj.w == mys && (j + 3) < i0);
  }
  kflag[g * n_per + i0] = (rank < K) ? 1 : 0;
}

// ---- compaction: per-graph scan of keep flags; aux={keep,score} for layer1 ----
__global__ __launch_bounds__(1024)
void compact_kernel(const float* __restrict__ scr, const int* __restrict__ kflag,
                    int n_per, int K, int* __restrict__ perm,
                    float* __restrict__ gsc, int2* __restrict__ aux) {
  __shared__ int wsum[16];
  const int g = blockIdx.x, i = threadIdx.x;
  const int keep = (i < n_per) ? kflag[g * n_per + i] : 0;
  const int incl = block_scan_1024(keep, wsum);
  if (i < n_per) {
    const float sc = scr[g * n_per + i];
    if (keep) {
      const int pos = incl - 1;
      perm[g * K + pos] = g * n_per + i;
      gsc[g * K + pos]  = sc;
    }
    if (aux) aux[g * n_per + i] = make_int2(keep, __float_as_int(sc));
  }
}

// ---- readout stage 1: per-(graph, row-chunk) partial mean/max over gated rows ----
__global__ __launch_bounds__(256)
void readout_part(const float* __restrict__ h, const int* __restrict__ perm,
                  const float* __restrict__ gsc, int K,
                  float* __restrict__ psum, float* __restrict__ pmax) {
  const int g     = blockIdx.x >> 4;
  const int chunk = blockIdx.x & (kRChunks - 1);
  const int j     = threadIdx.x & 127;
  const int part  = threadIdx.x >> 7;            // 2 parts
  const int rows  = (K + kRChunks - 1) / kRChunks;
  const int r0 = chunk * rows;
  const int r1 = min(r0 + rows, K);
  float sum = 0.0f, mx = -1e30f;
  for (int r = r0 + part; r < r1; r += 2) {
    const int   row = perm[g * K + r];
    const float sc  = gsc[g * K + r];
    const float v   = h[(size_t)row * kH + j] * sc;
    sum += v;
    mx = fmaxf(mx, v);
  }
  __shared__ float ss[2][128], sm[2][128];
  ss[part][j] = sum;
  sm[part][j] = mx;
  __syncthreads();
  if (part == 0) {
    sum += ss[1][j];
    mx = fmaxf(mx, sm[1][j]);
    psum[(size_t)blockIdx.x * 128 + j] = sum;
    pmax[(size_t)blockIdx.x * 128 + j] = mx;
  }
}

// ---- fused: combine readout chunks (both layers) + 2-layer MLP head ----
__global__ __launch_bounds__(128)
void final_mlp(const float* __restrict__ ps1, const float* __restrict__ pm1,
               const float* __restrict__ ps2, const float* __restrict__ pm2,
               const float* __restrict__ fW1, const float* __restrict__ fb1,
               const float* __restrict__ fW2, const float* __restrict__ fb2,
               float* __restrict__ out) {
  __shared__ float xx[256];
  __shared__ float z[128];
  const int g = blockIdx.x, tid = threadIdx.x;
  float s1 = 0.f, m1 = -1e30f, s2 = 0.f, m2 = -1e30f;
#pragma unroll
  for (int c = 0; c < kRChunks; ++c) {
    s1 += ps1[(size_t)(g * kRChunks + c) * 128 + tid];
    m1 = fmaxf(m1, pm1[(size_t)(g * kRChunks + c) * 128 + tid]);
    s2 += ps2[(size_t)(g * kRChunks + c) * 128 + tid];
    m2 = fmaxf(m2, pm2[(size_t)(g * kRChunks + c) * 128 + tid]);
  }
  xx[tid]       = s1 / (float)kK1 + s2 / (float)kK2;
  xx[tid + 128] = m1 + m2;
  __syncthreads();
  float a = fb1[tid];
  for (int k = 0; k < 256; ++k) a += xx[k] * fW1[k * 128 + tid];
  z[tid] = fmaxf(a, 0.0f);
  __syncthreads();
  if (tid < 10) {
    float o = fb2[tid];
    for (int k = 0; k < 128; ++k) o += z[k] * fW2[k * 10 + tid];
    out[g * 10 + tid] = o;
  }
}

}  // namespace

extern "C" void kernel_launch(void* const* d_in, const int* in_sizes, int n_in,
                              void* d_out, int out_size, void* d_ws, size_t ws_size,
                              hipStream_t stream) {
  const float* x   = (const float*)d_in[0];
  const int*   ei  = (const int*)d_in[1];
  const float* Wl1 = (const float*)d_in[3];
  const float* bl1 = (const float*)d_in[4];
  const float* Wr1 = (const float*)d_in[5];
  const float* Wl2 = (const float*)d_in[6];
  const float* bl2 = (const float*)d_in[7];
  const float* Wr2 = (const float*)d_in[8];
  const float* pw1 = (const float*)d_in[9];
  const float* pw2 = (const float*)d_in[10];
  const float* fW1 = (const float*)d_in[11];
  const float* fb1 = (const float*)d_in[12];
  const float* fW2 = (const float*)d_in[13];
  const float* fb2 = (const float*)d_in[14];
  const int* src = ei;
  const int* dst = ei + kE;
  (void)in_sizes; (void)n_in; (void)out_size; (void)ws_size;

  char* wsb = (char*)d_ws;
  size_t off_b = 0;
  auto alloc = [&](size_t bytes) {
    void* p = wsb + off_b;
    off_b += (bytes + 255) & ~(size_t)255;
    return p;
  };
  float* bufA = (float*)alloc((size_t)kM1 * kH * 4);  // mean1 -> mean2
  float* bufB = (float*)alloc((size_t)kM1 * kH * 4);  // h1
  float* bufC = (float*)alloc((size_t)kM2 * kH * 4);  // h2
  int*   deg  = (int*)alloc((size_t)kM1 * 4);
  int*   coff = (int*)alloc((size_t)kM1 * 4);
  int*   ccur = (int*)alloc((size_t)kM1 * 4);
  int*   ent  = (int*)alloc((size_t)kE * 4);
  int2*  ent2 = (int2*)alloc((size_t)kE * 8);
  float* scr  = (float*)alloc((size_t)kM1 * 4);
  int*   kflag= (int*)alloc((size_t)kM1 * 4);
  int2*  aux  = (int2*)alloc((size_t)kM1 * 8);
  int*   perm1= (int*)alloc((size_t)kM2 * 4);
  float* gsc1 = (float*)alloc((size_t)kM2 * 4);
  int*   perm2= (int*)alloc((size_t)kM3 * 4);
  float* gsc2 = (float*)alloc((size_t)kM3 * 4);
  float* psum1= (float*)alloc((size_t)kB * kRChunks * 128 * 4);
  float* pmax1= (float*)alloc((size_t)kB * kRChunks * 128 * 4);
  float* psum2= (float*)alloc((size_t)kB * kRChunks * 128 * 4);
  float* pmax2= (float*)alloc((size_t)kB * kRChunks * 128 * 4);
  ushort* wt1h = (ushort*)alloc((size_t)128 * 256 * 2);
  ushort* wt1l = (ushort*)alloc((size_t)128 * 256 * 2);
  ushort* wt2h = (ushort*)alloc((size_t)128 * 256 * 2);
  ushort* wt2l = (ushort*)alloc((size_t)128 * 256 * 2);
  float* pwn1 = (float*)alloc(128 * 4);
  float* pwn2 = (float*)alloc(128 * 4);

  prep_kernel<<<257, 256, 0, stream>>>(Wl1, Wr1, Wl2, Wr2, pw1, pw2,
                                       wt1h, wt1l, wt2h, wt2l, pwn1, pwn2);

  // ---------------- layer 1 ----------------
  hipMemsetAsync(deg, 0, (size_t)kM1 * 4, stream);
  deg_kernel<<<kE / 256, 256, 0, stream>>>(dst, deg);
  scan_kernel<<<kB, 1024, 0, stream>>>(deg, kN, coff, ccur);
  fill1_kernel<<<kE / 256, 256, 0, stream>>>(src, dst, ccur, ent);
  gather1_lds<<<kB * 8, 1024, 0, stream>>>(x, ent, coff, ccur, bufA);
  sage_gemm_mfma<<<kM1 / 64, 256, 0, stream>>>(bufA, x, nullptr, nullptr,
                                               wt1h, wt1l, bl1, pwn1, bufB, scr);
  rank_kernel<<<kB * 4, 256, 0, stream>>>(scr, kN, kK1, kflag);
  compact_kernel<<<kB, 1024, 0, stream>>>(scr, kflag, kN, kK1, perm1, gsc1, aux);
  readout_part<<<kB * kRChunks, 256, 0, stream>>>(bufB, perm1, gsc1, kK1, psum1, pmax1);

  // ---------------- layer 2 (reuses layer-1 CSR; ent2 folds aux in) ----------------
  ent2prep_kernel<<<kE / 256, 256, 0, stream>>>(ent, aux, ent2);
  gather2_lds<<<kB * 8, 1024, 0, stream>>>(bufB, ent2, coff, ccur, perm1, bufA);
  sage_gemm_mfma<<<kM2 / 64, 256, 0, stream>>>(bufA, bufB, perm1, gsc1,
                                               wt2h, wt2l, bl2, pwn2, bufC, scr);
  rank_kernel<<<kB * 4, 256, 0, stream>>>(scr, kK1, kK2, kflag);
  compact_kernel<<<kB, 1024, 0, stream>>>(scr, kflag, kK1, kK2, perm2, gsc2, nullptr);
  readout_part<<<kB * kRChunks, 256, 0, stream>>>(bufC, perm2, gsc2, kK2, psum2, pmax2);

  // ---------------- head ----------------
  final_mlp<<<kB, 128, 0, stream>>>(psum1, pmax1, psum2, pmax2,
                                    fW1, fb1, fW2, fb2, (float*)d_out);
}

// Round 3
// 334.052 us; speedup vs baseline: 1.2284x; 1.0878x over previous
//
#include <hip/hip_runtime.h>
#include <cstdint>
#include <cstddef>

namespace {

constexpr int kB    = 64;
constexpr int kN    = 1024;
constexpr int kE    = 655360;
constexpr int kEper = kE / kB;     // 10240
constexpr int kH    = 128;
constexpr int kK1   = 820;
constexpr int kK2   = 656;
constexpr int kM1   = kB * kN;     // 65536
constexpr int kM2   = kB * kK1;    // 52480
constexpr int kM3   = kB * kK2;    // 41984
constexpr int kRChunks = 16;       // readout row-chunks per graph

typedef __attribute__((ext_vector_type(8))) short bf16x8;
typedef __attribute__((ext_vector_type(4))) float f32x4;

__device__ inline ushort f2bf(float f) {            // fp32 -> bf16 RNE bits
  uint u = __float_as_uint(f);
  return (ushort)((u + 0x7fffu + ((u >> 16) & 1u)) >> 16);
}
__device__ inline float bf2f(ushort s) { return __uint_as_float(((uint)s) << 16); }

// inclusive block scan over 1024 threads: wave shfl-scan + 16-wavesum scan.
__device__ inline int block_scan_1024(int v, int* wsum /* LDS int[16] */) {
  const int lane = threadIdx.x & 63;
  const int w    = threadIdx.x >> 6;
#pragma unroll
  for (int off = 1; off < 64; off <<= 1) {
    const int n = __shfl_up(v, off);
    if (lane >= off) v += n;
  }
  if (lane == 63) wsum[w] = v;
  __syncthreads();
  if (w == 0) {
    int s = (lane < 16) ? wsum[lane] : 0;
#pragma unroll
    for (int off = 1; off < 16; off <<= 1) {
      const int n = __shfl_up(s, off);
      if (lane >= off) s += n;
    }
    if (lane < 16) wsum[lane] = s;
  }
  __syncthreads();
  if (w > 0) v += wsum[w - 1];
  return v;
}

// ================= prep: W^T hi/lo split + pw normalize =================
__global__ __launch_bounds__(256)
void prep_kernel(const float* __restrict__ Wl1, const float* __restrict__ Wr1,
                 const float* __restrict__ Wl2, const float* __restrict__ Wr2,
                 const float* __restrict__ pw1, const float* __restrict__ pw2,
                 ushort* __restrict__ W1h, ushort* __restrict__ W1l,
                 ushort* __restrict__ W2h, ushort* __restrict__ W2l,
                 float* __restrict__ pwn1, float* __restrict__ pwn2) {
  const int tid = threadIdx.x;
  if (blockIdx.x == 256) {
    __shared__ float sq[256];
    const float* pw = (tid < 128) ? pw1 : pw2;
    const int j = tid & 127;
    const float v = pw[j];
    sq[tid] = v * v;
    __syncthreads();
    const int base = (tid < 128) ? 0 : 128;
    float sum = 0.0f;
    for (int k = 0; k < 128; ++k) sum += sq[base + k];
    float* o = (tid < 128) ? pwn1 : pwn2;
    o[j] = v / sqrtf(sum);
    return;
  }
  const bool l2 = blockIdx.x >= 128;
  const int idx = (blockIdx.x & 127) * 256 + tid;   // 0..32767
  const int n = idx >> 8, k = idx & 255;
  const float* Wl = l2 ? Wl2 : Wl1;
  const float* Wr = l2 ? Wr2 : Wr1;
  const float w = (k < 128) ? Wl[k * kH + n] : Wr[(k - 128) * kH + n];
  const ushort h = f2bf(w);
  (l2 ? W2h : W1h)[n * 256 + k] = h;
  (l2 ? W2l : W1l)[n * 256 + k] = f2bf(w - bf2f(h));
}

// ================= fused CSR build (R14): memset+deg+scan+fill in ONE kernel ====
// One block per graph; LDS counting sort. Replaces 3 kernels + memset + 655K
// global atomics with LDS atomics (per-graph window). ent stores GRAPH-LOCAL ids.
// ccur is written as the END offset directly (old pipeline's post-fill cursor).
__global__ __launch_bounds__(1024)
void csr_build(const int* __restrict__ src, const int* __restrict__ dst,
               int* __restrict__ coff, int* __restrict__ ccur,
               int* __restrict__ ent) {
  __shared__ int cnt[1024];
  __shared__ int wsum[16];
  const int g   = blockIdx.x;
  const int tid = threadIdx.x;
  const int ebase = g * kEper;
  cnt[tid] = 0;
  __syncthreads();
  // pass 1: degree count (LDS atomics)
  for (int e = tid; e < kEper; e += 1024)
    atomicAdd(&cnt[dst[ebase + e] & (kN - 1)], 1);
  __syncthreads();
  const int dg   = cnt[tid];
  const int incl = block_scan_1024(dg, wsum);        // internal barriers
  const int start = ebase + incl - dg;               // exclusive scan
  coff[g * kN + tid] = start;
  ccur[g * kN + tid] = start + dg;                   // end offset
  __syncthreads();
  cnt[tid] = start;                                  // repurpose as cursor
  __syncthreads();
  // pass 2: place graph-local src ids
  for (int e = tid; e < kEper; e += 1024) {
    const int d   = dst[ebase + e] & (kN - 1);
    const int pos = atomicAdd(&cnt[d], 1);
    ent[pos] = src[ebase + e] & (kN - 1);
  }
}

// ================= LDS-staged gather-mean (v2, unchanged from R13) =================
// block = (graph, 16-col chunk); 64 KB feature slab in LDS; 4-lane group per
// node, one ds_read_b128 slot per edge (1024 B payload/wave-instr), edge ids
// hw-broadcast (same addr per 4 lanes), prefetched one body ahead.
__global__ __launch_bounds__(1024, 8)
void gather1_lds(const float* __restrict__ feat, const int* __restrict__ ent,
                 const int* __restrict__ off, const int* __restrict__ cursor,
                 float* __restrict__ aggout) {
  __shared__ float cache[1024 * 16];                 // 64 KB, stride 16 floats
  const int xcd   = blockIdx.x & 7;
  const int local = blockIdx.x >> 3;
  const int graph = xcd * 8 + (local >> 3);
  const int chunk = local & 7;
  const int tid   = threadIdx.x;
  const int gbase = graph << 10;

  // ---- stage: 1024 rows x 16 cols (64-B segments, 4 lanes/row) ----
#pragma unroll
  for (int ps = 0; ps < 4; ++ps) {
    const int row = ps * 256 + (tid >> 2);
    const int q   = (tid & 3) * 4;
    const float4 v = *(const float4*)(feat + (size_t)(gbase + row) * kH + chunk * 16 + q);
    *(float4*)&cache[row * 16 + q] = v;
  }
  __syncthreads();

  const int grp = tid >> 2;            // group id 0..255 = node within iter
  const int q4  = (tid & 3) * 4;       // this lane's 4 cols inside the chunk

  for (int it = 0; it < 4; ++it) {
    const int lnode = it * 256 + grp;
    const int node  = gbase + lnode;
    const int o0 = off[node];
    const int o1 = cursor[node];
    const int deg = o1 - o0;
    float4 acc = make_float4(0.f, 0.f, 0.f, 0.f);
    int pf[4];
#pragma unroll
    for (int i = 0; i < 4; ++i) pf[i] = (o0 + i < o1) ? ent[o0 + i] : 0;
    for (int eb = 0; eb < deg; eb += 4) {
      int nx[4];
#pragma unroll
      for (int i = 0; i < 4; ++i) {
        const int idx = o0 + eb + 4 + i;
        nx[i] = (idx < o1) ? ent[idx] : 0;
      }
#pragma unroll
      for (int i = 0; i < 4; ++i) {
        const float m = (eb + i < deg) ? 1.0f : 0.0f;   // mask tail (row 0 reads broadcast, free)
        const float4 v = *(const float4*)&cache[pf[i] * 16 + q4];
        acc.x = fmaf(v.x, m, acc.x);
        acc.y = fmaf(v.y, m, acc.y);
        acc.z = fmaf(v.z, m, acc.z);
        acc.w = fmaf(v.w, m, acc.w);
      }
#pragma unroll
      for (int i = 0; i < 4; ++i) pf[i] = nx[i];
    }
    const float r = 1.0f / fmaxf((float)deg, 1.0f);
    const f32x4 res = {acc.x * r, acc.y * r, acc.z * r, acc.w * r};
    __builtin_nontemporal_store(res, (f32x4*)(aggout + (size_t)node * kH + chunk * 16 + q4));
  }
}

// layer-2 variant (v3, R14): ent2/ent2prep deleted. Raw ent (4 B/edge) + the
// per-graph gated-score table gsg staged in LDS (4 KB): gs[l] = keep ? sc+2 : 0.
// Per edge: one ds_read_b128 (features) + one ds_read_b32 (gate). Tail edges
// masked by (eb+i<deg). cnt counts kept edges only.
__global__ __launch_bounds__(1024, 8)
void gather2_lds(const float* __restrict__ feat, const int* __restrict__ ent,
                 const int* __restrict__ off, const int* __restrict__ cursor,
                 const int* __restrict__ perm, const float* __restrict__ gsg,
                 float* __restrict__ aggout) {
  __shared__ float cache[1024 * 16];                 // 64 KB
  __shared__ float gs[1024];                         // 4 KB gated scores
  const int xcd   = blockIdx.x & 7;
  const int local = blockIdx.x >> 3;
  const int graph = xcd * 8 + (local >> 3);
  const int chunk = local & 7;
  const int tid   = threadIdx.x;
  const int gbase = graph << 10;

#pragma unroll
  for (int ps = 0; ps < 4; ++ps) {
    const int row = ps * 256 + (tid >> 2);
    const int q   = (tid & 3) * 4;
    const float4 v = *(const float4*)(feat + (size_t)(gbase + row) * kH + chunk * 16 + q);
    *(float4*)&cache[row * 16 + q] = v;
  }
  gs[tid] = gsg[gbase + tid];
  __syncthreads();

  const int grp = tid >> 2;
  const int q4  = (tid & 3) * 4;

  for (int it = 0; it < 4; ++it) {
    const int lnode = it * 256 + grp;                // valid < kK1 (820)
    int o0 = 0, o1 = 0;
    if (lnode < kK1) {
      const int orig = perm[graph * kK1 + lnode];
      o0 = off[orig];
      o1 = cursor[orig];
    }
    const int deg = o1 - o0;
    float4 acc = make_float4(0.f, 0.f, 0.f, 0.f);
    int cnt = 0;
    int pf[4];
#pragma unroll
    for (int i = 0; i < 4; ++i) pf[i] = (o0 + i < o1) ? ent[o0 + i] : 0;
    for (int eb = 0; eb < deg; eb += 4) {
      int nx[4];
#pragma unroll
      for (int i = 0; i < 4; ++i) {
        const int idx = o0 + eb + 4 + i;
        nx[i] = (idx < o1) ? ent[idx] : 0;
      }
#pragma unroll
      for (int i = 0; i < 4; ++i) {
        const float raw  = gs[pf[i]];
        const bool  kept = (raw > 0.5f) && (eb + i < deg);
        const float s    = kept ? raw - 2.0f : 0.0f;
        cnt += kept ? 1 : 0;
        const float4 v = *(const float4*)&cache[pf[i] * 16 + q4];
        acc.x = fmaf(v.x, s, acc.x);
        acc.y = fmaf(v.y, s, acc.y);
        acc.z = fmaf(v.z, s, acc.z);
        acc.w = fmaf(v.w, s, acc.w);
      }
#pragma unroll
      for (int i = 0; i < 4; ++i) pf[i] = nx[i];
    }
    const float r = 1.0f / fmaxf((float)cnt, 1.0f);
    const f32x4 res = {acc.x * r, acc.y * r, acc.z * r, acc.w * r};
    if (lnode < kK1)
      __builtin_nontemporal_store(res,
          (f32x4*)(aggout + (size_t)(graph * kK1 + lnode) * kH + chunk * 16 + q4));
  }
}

// ================= split-bf16 MFMA SAGE GEMM + fused score =================
// 64-row x 128-col block tile, 4 waves in 2x2, wave tile 32x64 (rt=2, ct=4).
__global__ __launch_bounds__(256)
void sage_gemm_mfma(const float* __restrict__ meanb, const float* __restrict__ xsrc,
                    const int* __restrict__ perm, const float* __restrict__ gsc,
                    const ushort* __restrict__ WTh, const ushort* __restrict__ WTl,
                    const float* __restrict__ bias, const float* __restrict__ pwn,
                    float* __restrict__ outp, float* __restrict__ scr) {
  __shared__ __align__(16) ushort aH[64][32];    // [row][k], 64 B row stride
  __shared__ __align__(16) ushort aL[64][32];
  __shared__ __align__(16) ushort wHs[128][32];  // [n][k] (= W^T)
  __shared__ __align__(16) ushort wLs[128][32];
  __shared__ float sdot[64][2];                  // [row][col-half] score partials
  const int tid  = threadIdx.x;
  const int wid  = tid >> 6;
  const int lane = tid & 63;
  const int quad = lane >> 4;
  const int l16  = lane & 15;
  const int rowbase = blockIdx.x * 64;
  const int wr = (wid >> 1) * 32;                // wave row offset (0/32)
  const int wc = (wid & 1) * 64;                 // wave col offset (0/64)

  f32x4 acc[2][4];
#pragma unroll
  for (int a = 0; a < 2; ++a)
#pragma unroll
    for (int b = 0; b < 4; ++b) acc[a][b] = (f32x4){0.f, 0.f, 0.f, 0.f};

  for (int s = 0; s < 8; ++s) {                  // 8 k-steps of 32 over K=256
    const bool ismean = s < 4;
    const float* sp = ismean ? meanb : xsrc;
    const int kbase = s * 32;
    const int kloc  = ismean ? kbase : kbase - 128;
    // ---- stage A (fp32 -> bf16 hi/lo): 64 rows x 32 k ----
#pragma unroll
    for (int i = 0; i < 2; ++i) {
      const int p   = tid + i * 256;
      const int row = p >> 3;
      const int k4  = (p & 7) * 4;
      const int grow = rowbase + row;
      int srow = grow; float scale = 1.0f;
      if (perm) { if (!ismean) { srow = perm[grow]; scale = gsc[grow]; } }
      const float4 v = *(const float4*)(sp + (size_t)srow * kH + kloc + k4);
      float f[4] = {v.x * scale, v.y * scale, v.z * scale, v.w * scale};
      ushort4 hv, lv;
      hv.x = f2bf(f[0]); lv.x = f2bf(f[0] - bf2f(hv.x));
      hv.y = f2bf(f[1]); lv.y = f2bf(f[1] - bf2f(hv.y));
      hv.z = f2bf(f[2]); lv.z = f2bf(f[2] - bf2f(hv.z));
      hv.w = f2bf(f[3]); lv.w = f2bf(f[3] - bf2f(hv.w));
      *(ushort4*)&aH[row][k4] = hv;
      *(ushort4*)&aL[row][k4] = lv;
    }
    // ---- stage W^T hi/lo: 128 n x 32 k ----
#pragma unroll
    for (int i = 0; i < 4; ++i) {
      const int p  = tid + i * 256;
      const int n  = p >> 3;
      const int k4 = (p & 7) * 4;
      *(ushort4*)&wHs[n][k4] = *(const ushort4*)(WTh + n * 256 + kbase + k4);
      *(ushort4*)&wLs[n][k4] = *(const ushort4*)(WTl + n * 256 + kbase + k4);
    }
    __syncthreads();
    bf16x8 afh[2], afl[2];
#pragma unroll
    for (int rt = 0; rt < 2; ++rt) {
      afh[rt] = *(const bf16x8*)&aH[wr + rt * 16 + l16][quad * 8];
      afl[rt] = *(const bf16x8*)&aL[wr + rt * 16 + l16][quad * 8];
    }
#pragma unroll
    for (int ct = 0; ct < 4; ++ct) {
      const bf16x8 bh = *(const bf16x8*)&wHs[wc + ct * 16 + l16][quad * 8];
      const bf16x8 bl = *(const bf16x8*)&wLs[wc + ct * 16 + l16][quad * 8];
#pragma unroll
      for (int rt = 0; rt < 2; ++rt) {
        acc[rt][ct] = __builtin_amdgcn_mfma_f32_16x16x32_bf16(afh[rt], bh, acc[rt][ct], 0, 0, 0);
        acc[rt][ct] = __builtin_amdgcn_mfma_f32_16x16x32_bf16(afh[rt], bl, acc[rt][ct], 0, 0, 0);
        acc[rt][ct] = __builtin_amdgcn_mfma_f32_16x16x32_bf16(afl[rt], bh, acc[rt][ct], 0, 0, 0);
      }
    }
    __syncthreads();
  }
  // ---- epilogue: bias + relu + store + fused score (64-col partial/wave) ----
  float bv[4], pwv[4];
#pragma unroll
  for (int ct = 0; ct < 4; ++ct) {
    const int col = wc + ct * 16 + l16;
    bv[ct]  = bias[col];
    pwv[ct] = pwn[col];
  }
  float dot[2][4];
#pragma unroll
  for (int rt = 0; rt < 2; ++rt)
#pragma unroll
    for (int reg = 0; reg < 4; ++reg) dot[rt][reg] = 0.0f;
#pragma unroll
  for (int ct = 0; ct < 4; ++ct) {
    const int col = wc + ct * 16 + l16;
#pragma unroll
    for (int rt = 0; rt < 2; ++rt) {
#pragma unroll
      for (int reg = 0; reg < 4; ++reg) {
        const int row = rowbase + wr + rt * 16 + quad * 4 + reg;
        const float o = fmaxf(acc[rt][ct][reg] + bv[ct], 0.0f);
        outp[(size_t)row * kH + col] = o;
        dot[rt][reg] += o * pwv[ct];
      }
    }
  }
#pragma unroll
  for (int rt = 0; rt < 2; ++rt) {
#pragma unroll
    for (int reg = 0; reg < 4; ++reg) {
      float d = dot[rt][reg];
      d += __shfl_xor(d, 1);
      d += __shfl_xor(d, 2);
      d += __shfl_xor(d, 4);
      d += __shfl_xor(d, 8);
      if (l16 == 0) sdot[wr + rt * 16 + quad * 4 + reg][wc >> 6] = d;
    }
  }
  __syncthreads();
  if (tid < 64) scr[rowbase + tid] = tanhf(sdot[tid][0] + sdot[tid][1]);
}

// ================= fused top-K rank + compaction (R14) =================
// One block per graph. Scores staged once in LDS; each thread ranks its node
// (count of strictly-greater + equal-with-lower-index), keep = rank < K, then
// block-scan of keep flags writes perm/gsc. For layer 1 also emits the gated
// score table gsg[local] = keep ? score+2 : 0 consumed by gather2's LDS gate.
__global__ __launch_bounds__(1024)
void rank_compact(const float* __restrict__ scr, int n_per, int K,
                  int* __restrict__ perm, float* __restrict__ gsc,
                  float* __restrict__ gsg) {
  __shared__ __align__(16) float s[1024];
  __shared__ int wsum[16];
  const int g = blockIdx.x, tid = threadIdx.x;
  s[tid] = (tid < n_per) ? scr[g * n_per + tid] : -3e30f;   // pad never outranks
  __syncthreads();
  const float mys = s[tid];
  int rank = 0;
  for (int j = 0; j < 1024; j += 4) {
    const float4 sj = *(const float4*)&s[j];
    rank += (sj.x > mys) || (sj.x == mys && (j + 0) < tid);
    rank += (sj.y > mys) || (sj.y == mys && (j + 1) < tid);
    rank += (sj.z > mys) || (sj.z == mys && (j + 2) < tid);
    rank += (sj.w > mys) || (sj.w == mys && (j + 3) < tid);
  }
  const int keep = (tid < n_per && rank < K) ? 1 : 0;
  const int incl = block_scan_1024(keep, wsum);             // internal barriers
  if (keep) {
    perm[g * K + incl - 1] = g * n_per + tid;
    gsc[g * K + incl - 1]  = mys;
  }
  if (gsg) gsg[g * kN + tid] = keep ? mys + 2.0f : 0.0f;
}

// ---- readout stage 1: per-(graph, row-chunk) partial mean/max over gated rows ----
__global__ __launch_bounds__(256)
void readout_part(const float* __restrict__ h, const int* __restrict__ perm,
                  const float* __restrict__ gsc, int K,
                  float* __restrict__ psum, float* __restrict__ pmax) {
  const int g     = blockIdx.x >> 4;
  const int chunk = blockIdx.x & (kRChunks - 1);
  const int j     = threadIdx.x & 127;
  const int part  = threadIdx.x >> 7;            // 2 parts
  const int rows  = (K + kRChunks - 1) / kRChunks;
  const int r0 = chunk * rows;
  const int r1 = min(r0 + rows, K);
  float sum = 0.0f, mx = -1e30f;
  for (int r = r0 + part; r < r1; r += 2) {
    const int   row = perm[g * K + r];
    const float sc  = gsc[g * K + r];
    const float v   = h[(size_t)row * kH + j] * sc;
    sum += v;
    mx = fmaxf(mx, v);
  }
  __shared__ float ss[2][128], sm[2][128];
  ss[part][j] = sum;
  sm[part][j] = mx;
  __syncthreads();
  if (part == 0) {
    sum += ss[1][j];
    mx = fmaxf(mx, sm[1][j]);
    psum[(size_t)blockIdx.x * 128 + j] = sum;
    pmax[(size_t)blockIdx.x * 128 + j] = mx;
  }
}

// ---- fused: combine readout chunks (both layers) + 2-layer MLP head ----
__global__ __launch_bounds__(128)
void final_mlp(const float* __restrict__ ps1, const float* __restrict__ pm1,
               const float* __restrict__ ps2, const float* __restrict__ pm2,
               const float* __restrict__ fW1, const float* __restrict__ fb1,
               const float* __restrict__ fW2, const float* __restrict__ fb2,
               float* __restrict__ out) {
  __shared__ float xx[256];
  __shared__ float z[128];
  const int g = blockIdx.x, tid = threadIdx.x;
  float s1 = 0.f, m1 = -1e30f, s2 = 0.f, m2 = -1e30f;
#pragma unroll
  for (int c = 0; c < kRChunks; ++c) {
    s1 += ps1[(size_t)(g * kRChunks + c) * 128 + tid];
    m1 = fmaxf(m1, pm1[(size_t)(g * kRChunks + c) * 128 + tid]);
    s2 += ps2[(size_t)(g * kRChunks + c) * 128 + tid];
    m2 = fmaxf(m2, pm2[(size_t)(g * kRChunks + c) * 128 + tid]);
  }
  xx[tid]       = s1 / (float)kK1 + s2 / (float)kK2;
  xx[tid + 128] = m1 + m2;
  __syncthreads();
  float a = fb1[tid];
  for (int k = 0; k < 256; ++k) a += xx[k] * fW1[k * 128 + tid];
  z[tid] = fmaxf(a, 0.0f);
  __syncthreads();
  if (tid < 10) {
    float o = fb2[tid];
    for (int k = 0; k < 128; ++k) o += z[k] * fW2[k * 10 + tid];
    out[g * 10 + tid] = o;
  }
}

}  // namespace

extern "C" void kernel_launch(void* const* d_in, const int* in_sizes, int n_in,
                              void* d_out, int out_size, void* d_ws, size_t ws_size,
                              hipStream_t stream) {
  const float* x   = (const float*)d_in[0];
  const int*   ei  = (const int*)d_in[1];
  const float* Wl1 = (const float*)d_in[3];
  const float* bl1 = (const float*)d_in[4];
  const float* Wr1 = (const float*)d_in[5];
  const float* Wl2 = (const float*)d_in[6];
  const float* bl2 = (const float*)d_in[7];
  const float* Wr2 = (const float*)d_in[8];
  const float* pw1 = (const float*)d_in[9];
  const float* pw2 = (const float*)d_in[10];
  const float* fW1 = (const float*)d_in[11];
  const float* fb1 = (const float*)d_in[12];
  const float* fW2 = (const float*)d_in[13];
  const float* fb2 = (const float*)d_in[14];
  const int* src = ei;
  const int* dst = ei + kE;
  (void)in_sizes; (void)n_in; (void)out_size; (void)ws_size;

  char* wsb = (char*)d_ws;
  size_t off_b = 0;
  auto alloc = [&](size_t bytes) {
    void* p = wsb + off_b;
    off_b += (bytes + 255) & ~(size_t)255;
    return p;
  };
  float* bufA = (float*)alloc((size_t)kM1 * kH * 4);  // mean1 -> mean2
  float* bufB = (float*)alloc((size_t)kM1 * kH * 4);  // h1
  float* bufC = (float*)alloc((size_t)kM2 * kH * 4);  // h2
  int*   coff = (int*)alloc((size_t)kM1 * 4);
  int*   ccur = (int*)alloc((size_t)kM1 * 4);
  int*   ent  = (int*)alloc((size_t)kE * 4);
  float* scr  = (float*)alloc((size_t)kM1 * 4);
  float* gsg  = (float*)alloc((size_t)kM1 * 4);
  int*   perm1= (int*)alloc((size_t)kM2 * 4);
  float* gsc1 = (float*)alloc((size_t)kM2 * 4);
  int*   perm2= (int*)alloc((size_t)kM3 * 4);
  float* gsc2 = (float*)alloc((size_t)kM3 * 4);
  float* psum1= (float*)alloc((size_t)kB * kRChunks * 128 * 4);
  float* pmax1= (float*)alloc((size_t)kB * kRChunks * 128 * 4);
  float* psum2= (float*)alloc((size_t)kB * kRChunks * 128 * 4);
  float* pmax2= (float*)alloc((size_t)kB * kRChunks * 128 * 4);
  ushort* wt1h = (ushort*)alloc((size_t)128 * 256 * 2);
  ushort* wt1l = (ushort*)alloc((size_t)128 * 256 * 2);
  ushort* wt2h = (ushort*)alloc((size_t)128 * 256 * 2);
  ushort* wt2l = (ushort*)alloc((size_t)128 * 256 * 2);
  float* pwn1 = (float*)alloc(128 * 4);
  float* pwn2 = (float*)alloc(128 * 4);

  prep_kernel<<<257, 256, 0, stream>>>(Wl1, Wr1, Wl2, Wr2, pw1, pw2,
                                       wt1h, wt1l, wt2h, wt2l, pwn1, pwn2);

  // ---------------- layer 1 ----------------
  csr_build<<<kB, 1024, 0, stream>>>(src, dst, coff, ccur, ent);
  gather1_lds<<<kB * 8, 1024, 0, stream>>>(x, ent, coff, ccur, bufA);
  sage_gemm_mfma<<<kM1 / 64, 256, 0, stream>>>(bufA, x, nullptr, nullptr,
                                               wt1h, wt1l, bl1, pwn1, bufB, scr);
  rank_compact<<<kB, 1024, 0, stream>>>(scr, kN, kK1, perm1, gsc1, gsg);
  readout_part<<<kB * kRChunks, 256, 0, stream>>>(bufB, perm1, gsc1, kK1, psum1, pmax1);

  // ---------------- layer 2 (reuses layer-1 CSR; gate staged in gather2 LDS) ----
  gather2_lds<<<kB * 8, 1024, 0, stream>>>(bufB, ent, coff, ccur, perm1, gsg, bufA);
  sage_gemm_mfma<<<kM2 / 64, 256, 0, stream>>>(bufA, bufB, perm1, gsc1,
                                               wt2h, wt2l, bl2, pwn2, bufC, scr);
  rank_compact<<<kB, 1024, 0, stream>>>(scr, kK1, kK2, perm2, gsc2, nullptr);
  readout_part<<<kB * kRChunks, 256, 0, stream>>>(bufC, perm2, gsc2, kK2, psum2, pmax2);

  // ---------------- head ----------------
  final_mlp<<<kB, 128, 0, stream>>>(psum1, pmax1, psum2, pmax2,
                                    fW1, fb1, fW2, fb2, (float*)d_out);
}

// Round 5
// 269.685 us; speedup vs baseline: 1.5216x; 1.2387x over previous
//
#include <hip/hip_runtime.h>
#include <cstdint>
#include <cstddef>

namespace {

constexpr int kB    = 64;
constexpr int kN    = 1024;
constexpr int kE    = 655360;
constexpr int kEper = kE / kB;     // 10240
constexpr int kH    = 128;
constexpr int kK1   = 820;
constexpr int kK2   = 656;
constexpr int kM1   = kB * kN;     // 65536
constexpr int kM2   = kB * kK1;    // 52480
constexpr int kM3   = kB * kK2;    // 41984
constexpr int kRChunks = 16;       // readout row-chunks per graph

typedef __attribute__((ext_vector_type(8))) short bf16x8;
typedef __attribute__((ext_vector_type(4))) float f32x4;

__device__ inline ushort f2bf(float f) {            // fp32 -> bf16 RNE bits
  uint u = __float_as_uint(f);
  return (ushort)((u + 0x7fffu + ((u >> 16) & 1u)) >> 16);
}
__device__ inline float bf2f(ushort s) { return __uint_as_float(((uint)s) << 16); }

// inclusive block scan over 1024 threads: wave shfl-scan + 16-wavesum scan.
__device__ inline int block_scan_1024(int v, int* wsum /* LDS int[16] */) {
  const int lane = threadIdx.x & 63;
  const int w    = threadIdx.x >> 6;
#pragma unroll
  for (int off = 1; off < 64; off <<= 1) {
    const int n = __shfl_up(v, off);
    if (lane >= off) v += n;
  }
  if (lane == 63) wsum[w] = v;
  __syncthreads();
  if (w == 0) {
    int s = (lane < 16) ? wsum[lane] : 0;
#pragma unroll
    for (int off = 1; off < 16; off <<= 1) {
      const int n = __shfl_up(s, off);
      if (lane >= off) s += n;
    }
    if (lane < 16) wsum[lane] = s;
  }
  __syncthreads();
  if (w > 0) v += wsum[w - 1];
  return v;
}

// ================= prep: W^T hi/lo split + pw normalize =================
__global__ __launch_bounds__(256)
void prep_kernel(const float* __restrict__ Wl1, const float* __restrict__ Wr1,
                 const float* __restrict__ Wl2, const float* __restrict__ Wr2,
                 const float* __restrict__ pw1, const float* __restrict__ pw2,
                 ushort* __restrict__ W1h, ushort* __restrict__ W1l,
                 ushort* __restrict__ W2h, ushort* __restrict__ W2l,
                 float* __restrict__ pwn1, float* __restrict__ pwn2) {
  const int tid = threadIdx.x;
  if (blockIdx.x == 256) {
    __shared__ float sq[256];
    const float* pw = (tid < 128) ? pw1 : pw2;
    const int j = tid & 127;
    const float v = pw[j];
    sq[tid] = v * v;
    __syncthreads();
    const int base = (tid < 128) ? 0 : 128;
    float sum = 0.0f;
    for (int k = 0; k < 128; ++k) sum += sq[base + k];
    float* o = (tid < 128) ? pwn1 : pwn2;
    o[j] = v / sqrtf(sum);
    return;
  }
  const bool l2 = blockIdx.x >= 128;
  const int idx = (blockIdx.x & 127) * 256 + tid;   // 0..32767
  const int n = idx >> 8, k = idx & 255;
  const float* Wl = l2 ? Wl2 : Wl1;
  const float* Wr = l2 ? Wr2 : Wr1;
  const float w = (k < 128) ? Wl[k * kH + n] : Wr[(k - 128) * kH + n];
  const ushort h = f2bf(w);
  (l2 ? W2h : W1h)[n * 256 + k] = h;
  (l2 ? W2l : W1l)[n * 256 + k] = f2bf(w - bf2f(h));
}

// ================= fused CSR build: memset+deg+scan+fill in ONE kernel ====
// One block per graph; LDS counting sort. ent stores GRAPH-LOCAL ids.
__global__ __launch_bounds__(1024)
void csr_build(const int* __restrict__ src, const int* __restrict__ dst,
               int* __restrict__ coff, int* __restrict__ ccur,
               int* __restrict__ ent) {
  __shared__ int cnt[1024];
  __shared__ int wsum[16];
  const int g   = blockIdx.x;
  const int tid = threadIdx.x;
  const int ebase = g * kEper;
  cnt[tid] = 0;
  __syncthreads();
  // pass 1: degree count (LDS atomics)
  for (int e = tid; e < kEper; e += 1024)
    atomicAdd(&cnt[dst[ebase + e] & (kN - 1)], 1);
  __syncthreads();
  const int dg   = cnt[tid];
  const int incl = block_scan_1024(dg, wsum);        // internal barriers
  const int start = ebase + incl - dg;               // exclusive scan
  coff[g * kN + tid] = start;
  ccur[g * kN + tid] = start + dg;                   // end offset
  __syncthreads();
  cnt[tid] = start;                                  // repurpose as cursor
  __syncthreads();
  // pass 2: place graph-local src ids
  for (int e = tid; e < kEper; e += 1024) {
    const int d   = dst[ebase + e] & (kN - 1);
    const int pos = atomicAdd(&cnt[d], 1);
    ent[pos] = src[ebase + e] & (kN - 1);
  }
}

// ================= LDS-staged gather-mean (v2) =================
// block = (graph, 16-col chunk); 64 KB feature slab in LDS; 4-lane group per
// node, one ds_read_b128 slot per edge (1024 B payload/wave-instr), edge ids
// hw-broadcast (same addr per 4 lanes), prefetched one body ahead.
__global__ __launch_bounds__(1024, 8)
void gather1_lds(const float* __restrict__ feat, const int* __restrict__ ent,
                 const int* __restrict__ off, const int* __restrict__ cursor,
                 float* __restrict__ aggout) {
  __shared__ float cache[1024 * 16];                 // 64 KB, stride 16 floats
  const int xcd   = blockIdx.x & 7;
  const int local = blockIdx.x >> 3;
  const int graph = xcd * 8 + (local >> 3);
  const int chunk = local & 7;
  const int tid   = threadIdx.x;
  const int gbase = graph << 10;

  // ---- stage: 1024 rows x 16 cols (64-B segments, 4 lanes/row) ----
#pragma unroll
  for (int ps = 0; ps < 4; ++ps) {
    const int row = ps * 256 + (tid >> 2);
    const int q   = (tid & 3) * 4;
    const float4 v = *(const float4*)(feat + (size_t)(gbase + row) * kH + chunk * 16 + q);
    *(float4*)&cache[row * 16 + q] = v;
  }
  __syncthreads();

  const int grp = tid >> 2;            // group id 0..255 = node within iter
  const int q4  = (tid & 3) * 4;       // this lane's 4 cols inside the chunk

  for (int it = 0; it < 4; ++it) {
    const int lnode = it * 256 + grp;
    const int node  = gbase + lnode;
    const int o0 = off[node];
    const int o1 = cursor[node];
    const int deg = o1 - o0;
    float4 acc = make_float4(0.f, 0.f, 0.f, 0.f);
    int pf[4];
#pragma unroll
    for (int i = 0; i < 4; ++i) pf[i] = (o0 + i < o1) ? ent[o0 + i] : 0;
    for (int eb = 0; eb < deg; eb += 4) {
      int nx[4];
#pragma unroll
      for (int i = 0; i < 4; ++i) {
        const int idx = o0 + eb + 4 + i;
        nx[i] = (idx < o1) ? ent[idx] : 0;
      }
#pragma unroll
      for (int i = 0; i < 4; ++i) {
        const float m = (eb + i < deg) ? 1.0f : 0.0f;   // mask tail (row 0 reads broadcast, free)
        const float4 v = *(const float4*)&cache[pf[i] * 16 + q4];
        acc.x = fmaf(v.x, m, acc.x);
        acc.y = fmaf(v.y, m, acc.y);
        acc.z = fmaf(v.z, m, acc.z);
        acc.w = fmaf(v.w, m, acc.w);
      }
#pragma unroll
      for (int i = 0; i < 4; ++i) pf[i] = nx[i];
    }
    const float r = 1.0f / fmaxf((float)deg, 1.0f);
    const f32x4 res = {acc.x * r, acc.y * r, acc.z * r, acc.w * r};
    __builtin_nontemporal_store(res, (f32x4*)(aggout + (size_t)node * kH + chunk * 16 + q4));
  }
}

// layer-2 variant (v3): raw ent (4 B/edge) + per-graph gated-score table gsg
// staged in LDS (4 KB): gs[l] = keep ? sc+2 : 0. Per edge: one ds_read_b128
// (features) + one ds_read_b32 (gate). cnt counts kept edges only.
__global__ __launch_bounds__(1024, 8)
void gather2_lds(const float* __restrict__ feat, const int* __restrict__ ent,
                 const int* __restrict__ off, const int* __restrict__ cursor,
                 const int* __restrict__ perm, const float* __restrict__ gsg,
                 float* __restrict__ aggout) {
  __shared__ float cache[1024 * 16];                 // 64 KB
  __shared__ float gs[1024];                         // 4 KB gated scores
  const int xcd   = blockIdx.x & 7;
  const int local = blockIdx.x >> 3;
  const int graph = xcd * 8 + (local >> 3);
  const int chunk = local & 7;
  const int tid   = threadIdx.x;
  const int gbase = graph << 10;

#pragma unroll
  for (int ps = 0; ps < 4; ++ps) {
    const int row = ps * 256 + (tid >> 2);
    const int q   = (tid & 3) * 4;
    const float4 v = *(const float4*)(feat + (size_t)(gbase + row) * kH + chunk * 16 + q);
    *(float4*)&cache[row * 16 + q] = v;
  }
  gs[tid] = gsg[gbase + tid];
  __syncthreads();

  const int grp = tid >> 2;
  const int q4  = (tid & 3) * 4;

  for (int it = 0; it < 4; ++it) {
    const int lnode = it * 256 + grp;                // valid < kK1 (820)
    int o0 = 0, o1 = 0;
    if (lnode < kK1) {
      const int orig = perm[graph * kK1 + lnode];
      o0 = off[orig];
      o1 = cursor[orig];
    }
    const int deg = o1 - o0;
    float4 acc = make_float4(0.f, 0.f, 0.f, 0.f);
    int cnt = 0;
    int pf[4];
#pragma unroll
    for (int i = 0; i < 4; ++i) pf[i] = (o0 + i < o1) ? ent[o0 + i] : 0;
    for (int eb = 0; eb < deg; eb += 4) {
      int nx[4];
#pragma unroll
      for (int i = 0; i < 4; ++i) {
        const int idx = o0 + eb + 4 + i;
        nx[i] = (idx < o1) ? ent[idx] : 0;
      }
#pragma unroll
      for (int i = 0; i < 4; ++i) {
        const float raw  = gs[pf[i]];
        const bool  kept = (raw > 0.5f) && (eb + i < deg);
        const float s    = kept ? raw - 2.0f : 0.0f;
        cnt += kept ? 1 : 0;
        const float4 v = *(const float4*)&cache[pf[i] * 16 + q4];
        acc.x = fmaf(v.x, s, acc.x);
        acc.y = fmaf(v.y, s, acc.y);
        acc.z = fmaf(v.z, s, acc.z);
        acc.w = fmaf(v.w, s, acc.w);
      }
#pragma unroll
      for (int i = 0; i < 4; ++i) pf[i] = nx[i];
    }
    const float r = 1.0f / fmaxf((float)cnt, 1.0f);
    const f32x4 res = {acc.x * r, acc.y * r, acc.z * r, acc.w * r};
    if (lnode < kK1)
      __builtin_nontemporal_store(res,
          (f32x4*)(aggout + (size_t)(graph * kK1 + lnode) * kH + chunk * 16 + q4));
  }
}

// ================= split-bf16 MFMA SAGE GEMM + fused score =================
// 64-row x 128-col block tile, 4 waves in 2x2, wave tile 32x64 (rt=2, ct=4).
__global__ __launch_bounds__(256)
void sage_gemm_mfma(const float* __restrict__ meanb, const float* __restrict__ xsrc,
                    const int* __restrict__ perm, const float* __restrict__ gsc,
                    const ushort* __restrict__ WTh, const ushort* __restrict__ WTl,
                    const float* __restrict__ bias, const float* __restrict__ pwn,
                    float* __restrict__ outp, float* __restrict__ scr) {
  __shared__ __align__(16) ushort aH[64][32];    // [row][k], 64 B row stride
  __shared__ __align__(16) ushort aL[64][32];
  __shared__ __align__(16) ushort wHs[128][32];  // [n][k] (= W^T)
  __shared__ __align__(16) ushort wLs[128][32];
  __shared__ float sdot[64][2];                  // [row][col-half] score partials
  const int tid  = threadIdx.x;
  const int wid  = tid >> 6;
  const int lane = tid & 63;
  const int quad = lane >> 4;
  const int l16  = lane & 15;
  const int rowbase = blockIdx.x * 64;
  const int wr = (wid >> 1) * 32;                // wave row offset (0/32)
  const int wc = (wid & 1) * 64;                 // wave col offset (0/64)

  f32x4 acc[2][4];
#pragma unroll
  for (int a = 0; a < 2; ++a)
#pragma unroll
    for (int b = 0; b < 4; ++b) acc[a][b] = (f32x4){0.f, 0.f, 0.f, 0.f};

  for (int s = 0; s < 8; ++s) {                  // 8 k-steps of 32 over K=256
    const bool ismean = s < 4;
    const float* sp = ismean ? meanb : xsrc;
    const int kbase = s * 32;
    const int kloc  = ismean ? kbase : kbase - 128;
    // ---- stage A (fp32 -> bf16 hi/lo): 64 rows x 32 k ----
#pragma unroll
    for (int i = 0; i < 2; ++i) {
      const int p   = tid + i * 256;
      const int row = p >> 3;
      const int k4  = (p & 7) * 4;
      const int grow = rowbase + row;
      int srow = grow; float scale = 1.0f;
      if (perm) { if (!ismean) { srow = perm[grow]; scale = gsc[grow]; } }
      const float4 v = *(const float4*)(sp + (size_t)srow * kH + kloc + k4);
      float f[4] = {v.x * scale, v.y * scale, v.z * scale, v.w * scale};
      ushort4 hv, lv;
      hv.x = f2bf(f[0]); lv.x = f2bf(f[0] - bf2f(hv.x));
      hv.y = f2bf(f[1]); lv.y = f2bf(f[1] - bf2f(hv.y));
      hv.z = f2bf(f[2]); lv.z = f2bf(f[2] - bf2f(hv.z));
      hv.w = f2bf(f[3]); lv.w = f2bf(f[3] - bf2f(hv.w));
      *(ushort4*)&aH[row][k4] = hv;
      *(ushort4*)&aL[row][k4] = lv;
    }
    // ---- stage W^T hi/lo: 128 n x 32 k ----
#pragma unroll
    for (int i = 0; i < 4; ++i) {
      const int p  = tid + i * 256;
      const int n  = p >> 3;
      const int k4 = (p & 7) * 4;
      *(ushort4*)&wHs[n][k4] = *(const ushort4*)(WTh + n * 256 + kbase + k4);
      *(ushort4*)&wLs[n][k4] = *(const ushort4*)(WTl + n * 256 + kbase + k4);
    }
    __syncthreads();
    bf16x8 afh[2], afl[2];
#pragma unroll
    for (int rt = 0; rt < 2; ++rt) {
      afh[rt] = *(const bf16x8*)&aH[wr + rt * 16 + l16][quad * 8];
      afl[rt] = *(const bf16x8*)&aL[wr + rt * 16 + l16][quad * 8];
    }
#pragma unroll
    for (int ct = 0; ct < 4; ++ct) {
      const bf16x8 bh = *(const bf16x8*)&wHs[wc + ct * 16 + l16][quad * 8];
      const bf16x8 bl = *(const bf16x8*)&wLs[wc + ct * 16 + l16][quad * 8];
#pragma unroll
      for (int rt = 0; rt < 2; ++rt) {
        acc[rt][ct] = __builtin_amdgcn_mfma_f32_16x16x32_bf16(afh[rt], bh, acc[rt][ct], 0, 0, 0);
        acc[rt][ct] = __builtin_amdgcn_mfma_f32_16x16x32_bf16(afh[rt], bl, acc[rt][ct], 0, 0, 0);
        acc[rt][ct] = __builtin_amdgcn_mfma_f32_16x16x32_bf16(afl[rt], bh, acc[rt][ct], 0, 0, 0);
      }
    }
    __syncthreads();
  }
  // ---- epilogue: bias + relu + store + fused score (64-col partial/wave) ----
  float bv[4], pwv[4];
#pragma unroll
  for (int ct = 0; ct < 4; ++ct) {
    const int col = wc + ct * 16 + l16;
    bv[ct]  = bias[col];
    pwv[ct] = pwn[col];
  }
  float dot[2][4];
#pragma unroll
  for (int rt = 0; rt < 2; ++rt)
#pragma unroll
    for (int reg = 0; reg < 4; ++reg) dot[rt][reg] = 0.0f;
#pragma unroll
  for (int ct = 0; ct < 4; ++ct) {
    const int col = wc + ct * 16 + l16;
#pragma unroll
    for (int rt = 0; rt < 2; ++rt) {
#pragma unroll
      for (int reg = 0; reg < 4; ++reg) {
        const int row = rowbase + wr + rt * 16 + quad * 4 + reg;
        const float o = fmaxf(acc[rt][ct][reg] + bv[ct], 0.0f);
        outp[(size_t)row * kH + col] = o;
        dot[rt][reg] += o * pwv[ct];
      }
    }
  }
#pragma unroll
  for (int rt = 0; rt < 2; ++rt) {
#pragma unroll
    for (int reg = 0; reg < 4; ++reg) {
      float d = dot[rt][reg];
      d += __shfl_xor(d, 1);
      d += __shfl_xor(d, 2);
      d += __shfl_xor(d, 4);
      d += __shfl_xor(d, 8);
      if (l16 == 0) sdot[wr + rt * 16 + quad * 4 + reg][wc >> 6] = d;
    }
  }
  __syncthreads();
  if (tid < 64) scr[rowbase + tid] = tanhf(sdot[tid][0] + sdot[tid][1]);
}

// ================= fused top-K rank + compaction (radix select) =========
// 4-pass byte radix-select on order-preserving uint keys. Histogram from
// registers (no score staging); bin suffix-scan inside wave 0 only (4 bins/
// lane + shfl_down suffix scan, no extra barriers). Yields threshold key T and
// rem = #(==T) to keep (lowest-index-first). One packed block scan of
// (gt<<11)|eq gives keep AND compaction position: pos = gt_excl +
// min(eq_excl, rem). Exactly reproduces rank<K with index tie-break.
__global__ __launch_bounds__(1024)
void rank_compact(const float* __restrict__ scr, int n_per, int K,
                  int* __restrict__ perm, float* __restrict__ gsc,
                  float* __restrict__ gsg) {
  __shared__ int hist[256];
  __shared__ int wsum[16];
  __shared__ uint bT;
  __shared__ int bRem;
  const int g = blockIdx.x, tid = threadIdx.x;
  const float sc = (tid < n_per) ? scr[g * n_per + tid] : -3e30f;  // pad never wins
  const uint bits = __float_as_uint(sc);
  const uint key = (bits & 0x80000000u) ? ~bits : (bits | 0x80000000u);

  uint prefix = 0;
  int rem = K;
#pragma unroll
  for (int shift = 24; shift >= 0; shift -= 8) {
    if (tid < 256) hist[tid] = 0;
    __syncthreads();
    const uint mask = (shift == 24) ? 0u : (0xFFFFFFFFu << (shift + 8));
    if ((key & mask) == prefix)
      atomicAdd(&hist[(key >> shift) & 255], 1);
    __syncthreads();
    if (tid < 64) {
      const int h0 = hist[4 * tid + 0], h1 = hist[4 * tid + 1];
      const int h2 = hist[4 * tid + 2], h3 = hist[4 * tid + 3];
      const int loc = h0 + h1 + h2 + h3;
      int suf = loc;                       // inclusive suffix sum over lanes
#pragma unroll
      for (int d = 1; d < 64; d <<= 1) {
        const int o = __shfl_down(suf, d);
        if (tid + d < 64) suf += o;
      }
      const int above = suf - loc;         // strictly-higher lanes
      int hs[5];
      hs[4] = above;
      hs[3] = above + h3;
      hs[2] = hs[3] + h2;
      hs[1] = hs[2] + h1;
      hs[0] = hs[1] + h0;
#pragma unroll
      for (int q = 0; q < 4; ++q) {
        if (hs[q] >= rem && hs[q + 1] < rem) {   // unique crossing bin
          bT   = prefix | ((uint)(4 * tid + q) << shift);
          bRem = rem - hs[q + 1];
        }
      }
    }
    __syncthreads();
    prefix = bT;
    rem    = bRem;
  }
  // prefix == key of K-th largest; rem == #(==T) to keep (by lowest index).
  const int gt = (key > prefix) ? 1 : 0;
  const int eq = (key == prefix) ? 1 : 0;
  const int incl = block_scan_1024((gt << 11) | eq, wsum);   // internal barriers
  const int excl = incl - ((gt << 11) | eq);
  const int gt_excl = excl >> 11;
  const int eq_excl = excl & 2047;
  const int keep = (tid < n_per) && (gt || (eq && eq_excl < rem));
  if (keep) {
    const int pos = gt_excl + min(eq_excl, rem);
    perm[g * K + pos] = g * n_per + tid;
    gsc[g * K + pos]  = sc;
  }
  if (gsg) gsg[g * kN + tid] = keep ? sc + 2.0f : 0.0f;
}

// ---- readout stage 1: per-(graph, row-chunk) partial mean/max over gated rows ----
__global__ __launch_bounds__(256)
void readout_part(const float* __restrict__ h, const int* __restrict__ perm,
                  const float* __restrict__ gsc, int K,
                  float* __restrict__ psum, float* __restrict__ pmax) {
  const int g     = blockIdx.x >> 4;
  const int chunk = blockIdx.x & (kRChunks - 1);
  const int j     = threadIdx.x & 127;
  const int part  = threadIdx.x >> 7;            // 2 parts
  const int rows  = (K + kRChunks - 1) / kRChunks;
  const int r0 = chunk * rows;
  const int r1 = min(r0 + rows, K);
  float sum = 0.0f, mx = -1e30f;
  for (int r = r0 + part; r < r1; r += 2) {
    const int   row = perm[g * K + r];
    const float sc  = gsc[g * K + r];
    const float v   = h[(size_t)row * kH + j] * sc;
    sum += v;
    mx = fmaxf(mx, v);
  }
  __shared__ float ss[2][128], sm[2][128];
  ss[part][j] = sum;
  sm[part][j] = mx;
  __syncthreads();
  if (part == 0) {
    sum += ss[1][j];
    mx = fmaxf(mx, sm[1][j]);
    psum[(size_t)blockIdx.x * 128 + j] = sum;
    pmax[(size_t)blockIdx.x * 128 + j] = mx;
  }
}

// ---- fused: combine readout chunks (both layers) + 2-layer MLP head ----
__global__ __launch_bounds__(128)
void final_mlp(const float* __restrict__ ps1, const float* __restrict__ pm1,
               const float* __restrict__ ps2, const float* __restrict__ pm2,
               const float* __restrict__ fW1, const float* __restrict__ fb1,
               const float* __restrict__ fW2, const float* __restrict__ fb2,
               float* __restrict__ out) {
  __shared__ float xx[256];
  __shared__ float z[128];
  const int g = blockIdx.x, tid = threadIdx.x;
  float s1 = 0.f, m1 = -1e30f, s2 = 0.f, m2 = -1e30f;
#pragma unroll
  for (int c = 0; c < kRChunks; ++c) {
    s1 += ps1[(size_t)(g * kRChunks + c) * 128 + tid];
    m1 = fmaxf(m1, pm1[(size_t)(g * kRChunks + c) * 128 + tid]);
    s2 += ps2[(size_t)(g * kRChunks + c) * 128 + tid];
    m2 = fmaxf(m2, pm2[(size_t)(g * kRChunks + c) * 128 + tid]);
  }
  xx[tid]       = s1 / (float)kK1 + s2 / (float)kK2;
  xx[tid + 128] = m1 + m2;
  __syncthreads();
  float a = fb1[tid];
  for (int k = 0; k < 256; ++k) a += xx[k] * fW1[k * 128 + tid];
  z[tid] = fmaxf(a, 0.0f);
  __syncthreads();
  if (tid < 10) {
    float o = fb2[tid];
    for (int k = 0; k < 128; ++k) o += z[k] * fW2[k * 10 + tid];
    out[g * 10 + tid] = o;
  }
}

}  // namespace

extern "C" void kernel_launch(void* const* d_in, const int* in_sizes, int n_in,
                              void* d_out, int out_size, void* d_ws, size_t ws_size,
                              hipStream_t stream) {
  const float* x   = (const float*)d_in[0];
  const int*   ei  = (const int*)d_in[1];
  const float* Wl1 = (const float*)d_in[3];
  const float* bl1 = (const float*)d_in[4];
  const float* Wr1 = (const float*)d_in[5];
  const float* Wl2 = (const float*)d_in[6];
  const float* bl2 = (const float*)d_in[7];
  const float* Wr2 = (const float*)d_in[8];
  const float* pw1 = (const float*)d_in[9];
  const float* pw2 = (const float*)d_in[10];
  const float* fW1 = (const float*)d_in[11];
  const float* fb1 = (const float*)d_in[12];
  const float* fW2 = (const float*)d_in[13];
  const float* fb2 = (const float*)d_in[14];
  const int* src = ei;
  const int* dst = ei + kE;
  (void)in_sizes; (void)n_in; (void)out_size; (void)ws_size;

  char* wsb = (char*)d_ws;
  size_t off_b = 0;
  auto alloc = [&](size_t bytes) {
    void* p = wsb + off_b;
    off_b += (bytes + 255) & ~(size_t)255;
    return p;
  };
  float* bufA = (float*)alloc((size_t)kM1 * kH * 4);  // mean1 -> mean2
  float* bufB = (float*)alloc((size_t)kM1 * kH * 4);  // h1
  float* bufC = (float*)alloc((size_t)kM2 * kH * 4);  // h2
  int*   coff = (int*)alloc((size_t)kM1 * 4);
  int*   ccur = (int*)alloc((size_t)kM1 * 4);
  int*   ent  = (int*)alloc((size_t)kE * 4);
  float* scr  = (float*)alloc((size_t)kM1 * 4);
  float* gsg  = (float*)alloc((size_t)kM1 * 4);
  int*   perm1= (int*)alloc((size_t)kM2 * 4);
  float* gsc1 = (float*)alloc((size_t)kM2 * 4);
  int*   perm2= (int*)alloc((size_t)kM3 * 4);
  float* gsc2 = (float*)alloc((size_t)kM3 * 4);
  float* psum1= (float*)alloc((size_t)kB * kRChunks * 128 * 4);
  float* pmax1= (float*)alloc((size_t)kB * kRChunks * 128 * 4);
  float* psum2= (float*)alloc((size_t)kB * kRChunks * 128 * 4);
  float* pmax2= (float*)alloc((size_t)kB * kRChunks * 128 * 4);
  ushort* wt1h = (ushort*)alloc((size_t)128 * 256 * 2);
  ushort* wt1l = (ushort*)alloc((size_t)128 * 256 * 2);
  ushort* wt2h = (ushort*)alloc((size_t)128 * 256 * 2);
  ushort* wt2l = (ushort*)alloc((size_t)128 * 256 * 2);
  float* pwn1 = (float*)alloc(128 * 4);
  float* pwn2 = (float*)alloc(128 * 4);

  prep_kernel<<<257, 256, 0, stream>>>(Wl1, Wr1, Wl2, Wr2, pw1, pw2,
                                       wt1h, wt1l, wt2h, wt2l, pwn1, pwn2);

  // ---------------- layer 1 ----------------
  csr_build<<<kB, 1024, 0, stream>>>(src, dst, coff, ccur, ent);
  gather1_lds<<<kB * 8, 1024, 0, stream>>>(x, ent, coff, ccur, bufA);
  sage_gemm_mfma<<<kM1 / 64, 256, 0, stream>>>(bufA, x, nullptr, nullptr,
                                               wt1h, wt1l, bl1, pwn1, bufB, scr);
  rank_compact<<<kB, 1024, 0, stream>>>(scr, kN, kK1, perm1, gsc1, gsg);
  readout_part<<<kB * kRChunks, 256, 0, stream>>>(bufB, perm1, gsc1, kK1, psum1, pmax1);

  // ---------------- layer 2 (reuses layer-1 CSR; gate staged in gather2 LDS) ----
  gather2_lds<<<kB * 8, 1024, 0, stream>>>(bufB, ent, coff, ccur, perm1, gsg, bufA);
  sage_gemm_mfma<<<kM2 / 64, 256, 0, stream>>>(bufA, bufB, perm1, gsc1,
                                               wt2h, wt2l, bl2, pwn2, bufC, scr);
  rank_compact<<<kB, 1024, 0, stream>>>(scr, kK1, kK2, perm2, gsc2, nullptr);
  readout_part<<<kB * kRChunks, 256, 0, stream>>>(bufC, perm2, gsc2, kK2, psum2, pmax2);

  // ---------------- head ----------------
  final_mlp<<<kB, 128, 0, stream>>>(psum1, pmax1, psum2, pmax2,
                                    fW1, fb1, fW2, fb2, (float*)d_out);
}